// Round 18
// baseline (348.648 us; speedup 1.0000x reference)
//
#include <hip/hip_runtime.h>
#include <math.h>

#define SEQ 2516
#define SEQP 2520
#define SEQP2 2560
#define CDIM 128

typedef __attribute__((ext_vector_type(8))) short short8;
typedef __attribute__((ext_vector_type(4))) float f32x4;

__device__ __forceinline__ float gelu_exact(float x) {
    return x * 0.5f * (1.0f + erff(x * 0.7071067811865475f));
}
__device__ __forceinline__ float fexp2(float x) { return __builtin_amdgcn_exp2f(x); }
__device__ __forceinline__ short f2bf(float f) {     // fp32 -> bf16 RNE
    unsigned u = __float_as_uint(f);
    unsigned r = 0x7fffu + ((u >> 16) & 1u);
    return (short)((u + r) >> 16);
}
__device__ __forceinline__ short f2bf_trunc(float f) {   // for P (e>=0): 1 op
    return (short)(__float_as_uint(f) >> 16);
}

// ---------------- concat + LN1(layer0): one wave per row ------------------------
__global__ __launch_bounds__(64) void concat_ln_kernel(
    const float* __restrict__ td, const float* __restrict__ sup,
    const float* __restrict__ g, const float* __restrict__ b,
    float* __restrict__ X, float* __restrict__ H) {
    const int row = blockIdx.x;
    const int t = threadIdx.x;
    float x0, x1;
    if (row < 16) {
        x0 = td[row * 128 + t];
        x1 = td[row * 128 + 64 + t];
    } else {
        int r = row - 16;
        int n = r / 100, p = r - n * 100;
        x0 = sup[n * 12800 + t * 100 + p];
        x1 = sup[n * 12800 + (t + 64) * 100 + p];
    }
    X[row * 128 + t] = x0;
    X[row * 128 + 64 + t] = x1;
    float s = x0 + x1;
    for (int off = 32; off > 0; off >>= 1) s += __shfl_down(s, off);
    float mean = __shfl(s, 0) * (1.f / 128.f);
    float d0 = x0 - mean, d1 = x1 - mean;
    float v = d0 * d0 + d1 * d1;
    for (int off = 32; off > 0; off >>= 1) v += __shfl_down(v, off);
    float var = __shfl(v, 0) * (1.f / 128.f);
    float rstd = rsqrtf(var + 1e-5f);
    H[row * 128 + t]      = d0 * rstd * g[t] + b[t];
    H[row * 128 + 64 + t] = d1 * rstd * g[t + 64] + b[t + 64];
}

// ---- qkv MFMA GEMM: writes Q prescaled bf16, K bf16 rows, V TRANSPOSED bf16 ----
__global__ __launch_bounds__(256) void qkv_mfma_kernel(
    const float* __restrict__ A, const float* __restrict__ W,
    const float* __restrict__ bias,
    short* __restrict__ Qbf, short* __restrict__ Kbf, short* __restrict__ VTb) {
    __shared__ __align__(16) short Wt[64 * 136];   // 17.4 KB
    const int t = threadIdx.x;
    const int wave = t >> 6, lane = t & 63;
    const int quad = lane >> 4, c16 = lane & 15;
    const int m0 = blockIdx.x * 64;
    const int n0 = blockIdx.y * 64;
    const float SC = 0.25f * 1.4426950408889634f;   // folded into Q
    #pragma unroll
    for (int pass = 0; pass < 4; ++pass) {
        int idx = t + pass * 256;
        int n = idx & 63, kc = idx >> 6;
        short8 wv;
        #pragma unroll
        for (int j = 0; j < 8; ++j)
            wv[j] = f2bf(W[(size_t)(kc * 8 + j) * 384 + n0 + n]);
        *(short8*)&Wt[n * 136 + kc * 8] = wv;
    }
    __syncthreads();
    const int am = m0 + wave * 16 + c16;
    f32x4 acc[4];
    #pragma unroll
    for (int i = 0; i < 4; ++i) acc[i] = (f32x4){0.f, 0.f, 0.f, 0.f};
    #pragma unroll
    for (int kk = 0; kk < 4; ++kk) {
        const float4* ap = (const float4*)(A + (size_t)am * 128 + kk * 32 + quad * 8);
        float4 a0 = ap[0], a1 = ap[1];
        short8 af;
        af[0] = f2bf(a0.x); af[1] = f2bf(a0.y); af[2] = f2bf(a0.z); af[3] = f2bf(a0.w);
        af[4] = f2bf(a1.x); af[5] = f2bf(a1.y); af[6] = f2bf(a1.z); af[7] = f2bf(a1.w);
        #pragma unroll
        for (int ns = 0; ns < 4; ++ns) {
            short8 wf = *(const short8*)&Wt[(ns * 16 + c16) * 136 + kk * 32 + quad * 8];
            acc[ns] = __builtin_amdgcn_mfma_f32_16x16x32_bf16(af, wf, acc[ns], 0, 0, 0);
        }
    }
    const int region = __builtin_amdgcn_readfirstlane(n0 >> 7);  // 0 Q, 1 K, 2 V
    #pragma unroll
    for (int ns = 0; ns < 4; ++ns) {
        const int n = n0 + ns * 16 + c16;
        float bv = bias[n];
        #pragma unroll
        for (int r = 0; r < 4; ++r) {
            const int row = m0 + wave * 16 + quad * 4 + r;
            float v = acc[ns][r] + bv;
            if (region == 0)      Qbf[(size_t)row * 128 + n] = f2bf(v * SC);
            else if (region == 1) Kbf[(size_t)row * 128 + (n - 128)] = f2bf(v);
            else                  VTb[(size_t)(n - 256) * SEQP2 + row] = f2bf(v);
        }
    }
}

// -------- MFMA bf16 GEMM (mlp1): C = gelu(A@W + bias) fp32 out ------------------
__global__ __launch_bounds__(256) void mfma_gemm_kernel(
    const float* __restrict__ A, const float* __restrict__ W,
    const float* __restrict__ bias, float* __restrict__ C, int M, int N) {
    __shared__ __align__(16) short Wt[64 * 136];
    const int t = threadIdx.x;
    const int wave = t >> 6, lane = t & 63;
    const int quad = lane >> 4, c16 = lane & 15;
    const int m0 = blockIdx.x * 64;
    const int n0 = blockIdx.y * 64;
    #pragma unroll
    for (int pass = 0; pass < 4; ++pass) {
        int idx = t + pass * 256;
        int n = idx & 63, kc = idx >> 6;
        short8 wv;
        #pragma unroll
        for (int j = 0; j < 8; ++j)
            wv[j] = f2bf(W[(size_t)(kc * 8 + j) * N + n0 + n]);
        *(short8*)&Wt[n * 136 + kc * 8] = wv;
    }
    __syncthreads();
    const int am = m0 + wave * 16 + c16;
    f32x4 acc[4];
    #pragma unroll
    for (int i = 0; i < 4; ++i) acc[i] = (f32x4){0.f, 0.f, 0.f, 0.f};
    #pragma unroll
    for (int kk = 0; kk < 4; ++kk) {
        const float4* ap = (const float4*)(A + (size_t)am * 128 + kk * 32 + quad * 8);
        float4 a0 = ap[0], a1 = ap[1];
        short8 af;
        af[0] = f2bf(a0.x); af[1] = f2bf(a0.y); af[2] = f2bf(a0.z); af[3] = f2bf(a0.w);
        af[4] = f2bf(a1.x); af[5] = f2bf(a1.y); af[6] = f2bf(a1.z); af[7] = f2bf(a1.w);
        #pragma unroll
        for (int ns = 0; ns < 4; ++ns) {
            short8 wf = *(const short8*)&Wt[(ns * 16 + c16) * 136 + kk * 32 + quad * 8];
            acc[ns] = __builtin_amdgcn_mfma_f32_16x16x32_bf16(af, wf, acc[ns], 0, 0, 0);
        }
    }
    #pragma unroll
    for (int ns = 0; ns < 4; ++ns) {
        const int n = n0 + ns * 16 + c16;
        float bv = bias[n];
        #pragma unroll
        for (int r = 0; r < 4; ++r) {
            int row = m0 + wave * 16 + quad * 4 + r;
            if (row < M) {
                float v = gelu_exact(acc[ns][r] + bv);
                C[(size_t)row * N + n] = v;
            }
        }
    }
}

// ---- mlp2 MFMA with K-split: grid (40 M-tiles, 8 K-splits of 64) ---------------
__global__ __launch_bounds__(256) void mfma_gemm_kpart_kernel(
    const float* __restrict__ A, const float* __restrict__ W,
    float* __restrict__ PARTG) {
    __shared__ __align__(16) short Wt[128 * 72];   // 18.4 KB
    const int t = threadIdx.x;
    const int wave = t >> 6, lane = t & 63;
    const int quad = lane >> 4, c16 = lane & 15;
    const int m0 = blockIdx.x * 64;
    const int kz = blockIdx.y;
    const int kbase = kz * 64;
    {
        const int n = t & 127, half = t >> 7;
        #pragma unroll
        for (int c = 0; c < 4; ++c) {
            short8 wv;
            #pragma unroll
            for (int j = 0; j < 8; ++j)
                wv[j] = f2bf(W[(size_t)(kbase + half * 32 + c * 8 + j) * 128 + n]);
            *(short8*)&Wt[n * 72 + half * 32 + c * 8] = wv;
        }
    }
    __syncthreads();
    const int am = m0 + wave * 16 + c16;
    f32x4 acc[8];
    #pragma unroll
    for (int i = 0; i < 8; ++i) acc[i] = (f32x4){0.f, 0.f, 0.f, 0.f};
    #pragma unroll
    for (int kk = 0; kk < 2; ++kk) {
        const float4* ap = (const float4*)(A + (size_t)am * 512 + kbase + kk * 32 + quad * 8);
        float4 a0 = ap[0], a1 = ap[1];
        short8 af;
        af[0] = f2bf(a0.x); af[1] = f2bf(a0.y); af[2] = f2bf(a0.z); af[3] = f2bf(a0.w);
        af[4] = f2bf(a1.x); af[5] = f2bf(a1.y); af[6] = f2bf(a1.z); af[7] = f2bf(a1.w);
        #pragma unroll
        for (int ns = 0; ns < 8; ++ns) {
            short8 wf = *(const short8*)&Wt[(ns * 16 + c16) * 72 + kk * 32 + quad * 8];
            acc[ns] = __builtin_amdgcn_mfma_f32_16x16x32_bf16(af, wf, acc[ns], 0, 0, 0);
        }
    }
    float* dst = PARTG + (size_t)kz * SEQP2 * 128;
    #pragma unroll
    for (int ns = 0; ns < 8; ++ns) {
        #pragma unroll
        for (int r = 0; r < 4; ++r) {
            const int row = m0 + wave * 16 + quad * 4 + r;
            dst[(size_t)row * 128 + ns * 16 + c16] = acc[ns][r];
        }
    }
}

// ---- combine 8 K-split partials + bias + residual + row-LN ---------------------
__global__ __launch_bounds__(512) void combine_ln_kernel(
    const float* __restrict__ PARTG, const float* __restrict__ bias,
    const float* __restrict__ R, float* __restrict__ C, float* __restrict__ H,
    const float* __restrict__ g, const float* __restrict__ bb, int M) {
    __shared__ float ln[8][130];
    const int t = threadIdx.x;
    const int c = t & 127;
    const int grp = __builtin_amdgcn_readfirstlane(t >> 7);
    const int r0 = blockIdx.x * 8 + grp * 2;
    #pragma unroll
    for (int i = 0; i < 2; ++i) {
        const int row = r0 + i;
        float v = bias[c] + R[(size_t)row * 128 + c];
        #pragma unroll
        for (int kz = 0; kz < 8; ++kz)
            v += PARTG[(size_t)kz * SEQP2 * 128 + (size_t)row * 128 + c];
        ln[grp * 2 + i][c] = v;
        if (row < M) C[(size_t)row * 128 + c] = v;
    }
    __syncthreads();
    const int wv = t >> 6, l = t & 63;
    float x0 = ln[wv][l], x1 = ln[wv][l + 64];
    float s = x0 + x1;
    for (int off = 32; off > 0; off >>= 1) s += __shfl_down(s, off);
    float mean = __shfl(s, 0) * (1.f / 128.f);
    float d0 = x0 - mean, d1 = x1 - mean;
    float vv = d0 * d0 + d1 * d1;
    for (int off = 32; off > 0; off >>= 1) vv += __shfl_down(vv, off);
    float var = __shfl(vv, 0) * (1.f / 128.f);
    float rstd = rsqrtf(var + 1e-5f);
    const int hrow = blockIdx.x * 8 + wv;
    H[(size_t)hrow * 128 + l]      = d0 * rstd * g[l] + bb[l];
    H[(size_t)hrow * 128 + 64 + l] = d1 * rstd * g[l + 64] + bb[l + 64];
}

// ------- skinny GEMM N=128 + residual + row-LN epilogue (proj, K=128) -----------
__global__ __launch_bounds__(512) void sgemm_ln_kernel(
    const float* __restrict__ A, const float* __restrict__ W,
    const float* __restrict__ bias, const float* __restrict__ R,
    float* __restrict__ C, float* __restrict__ H,
    const float* __restrict__ g, const float* __restrict__ bb, int M, int K) {
    __shared__ float ln[8][130];
    const int t = threadIdx.x;
    const int c = t & 127;
    const int grp = __builtin_amdgcn_readfirstlane(t >> 7);
    const int r0 = blockIdx.x * 8 + grp * 2;
    float acc0 = 0.f, acc1 = 0.f;
    #pragma unroll 4
    for (int k0 = 0; k0 < K; k0 += 4) {
        float w0 = W[(size_t)(k0 + 0) * 128 + c];
        float w1 = W[(size_t)(k0 + 1) * 128 + c];
        float w2 = W[(size_t)(k0 + 2) * 128 + c];
        float w3 = W[(size_t)(k0 + 3) * 128 + c];
        float4 a0 = *(const float4*)&A[(size_t)(r0 + 0) * K + k0];
        float4 a1 = *(const float4*)&A[(size_t)(r0 + 1) * K + k0];
        acc0 = fmaf(a0.x, w0, acc0); acc0 = fmaf(a0.y, w1, acc0);
        acc0 = fmaf(a0.z, w2, acc0); acc0 = fmaf(a0.w, w3, acc0);
        acc1 = fmaf(a1.x, w0, acc1); acc1 = fmaf(a1.y, w1, acc1);
        acc1 = fmaf(a1.z, w2, acc1); acc1 = fmaf(a1.w, w3, acc1);
    }
    float bv = bias[c];
    float v0 = acc0 + bv + R[(size_t)(r0 + 0) * 128 + c];
    float v1 = acc1 + bv + R[(size_t)(r0 + 1) * 128 + c];
    ln[grp * 2 + 0][c] = v0;
    ln[grp * 2 + 1][c] = v1;
    if (r0 + 0 < M) C[(size_t)(r0 + 0) * 128 + c] = v0;
    if (r0 + 1 < M) C[(size_t)(r0 + 1) * 128 + c] = v1;
    __syncthreads();
    const int wv = t >> 6, l = t & 63;
    float x0 = ln[wv][l], x1 = ln[wv][l + 64];
    float s = x0 + x1;
    for (int off = 32; off > 0; off >>= 1) s += __shfl_down(s, off);
    float mean = __shfl(s, 0) * (1.f / 128.f);
    float d0 = x0 - mean, d1 = x1 - mean;
    float vv = d0 * d0 + d1 * d1;
    for (int off = 32; off > 0; off >>= 1) vv += __shfl_down(vv, off);
    float var = __shfl(vv, 0) * (1.f / 128.f);
    float rstd = rsqrtf(var + 1e-5f);
    const int hrow = blockIdx.x * 8 + wv;
    H[(size_t)hrow * 128 + l]      = d0 * rstd * g[l] + bb[l];
    H[(size_t)hrow * 128 + 64 + l] = d1 * rstd * g[l + 64] + bb[l + 64];
}

// ---- attention: bf16 MFMA flash, pre-converted inputs, split-K=4 ---------------
// grid (79, 8 heads, 4 splits), block 128 (2 waves), 5 tiles of 128 keys each.
// 2528 blocks (vs 1264 at z=2): R17 counters still showed latency-bound
// (occupancy 18.5%, VALUBusy 40%); more+shorter blocks is the proven cure.
__global__ __launch_bounds__(128) void attn_kernel(
    const short* __restrict__ Qbf, const short* __restrict__ Kbf,
    const short* __restrict__ VTb, float* __restrict__ PART) {
    __shared__ __align__(16) short sKs[9600];  // Ks 128*24 | Vt 16*136 | P 2*16*136
    short* Ks = sKs;
    short* Vt = sKs + 3072;
    const int t = threadIdx.x;
    const int wave = t >> 6, lane = t & 63;
    const int quad = lane >> 4, c16 = lane & 15;
    short* Pw = sKs + 3072 + 2176 + wave * 16 * 136;
    const int head = blockIdx.y, z = blockIdx.z;
    const int qb = blockIdx.x * 32 + wave * 16;

    short8 qf;
    #pragma unroll
    for (int i = 0; i < 8; ++i) qf[i] = 0;
    if (quad < 2)
        qf = *(const short8*)(Qbf + (size_t)(qb + c16) * 128 + head * 16 + quad * 8);
    f32x4 oacc = {0.f, 0.f, 0.f, 0.f};
    float m_[4] = {-INFINITY, -INFINITY, -INFINITY, -INFINITY};
    float l_[4] = {0.f, 0.f, 0.f, 0.f};

    const int vdim = t >> 3, vseg = t & 7;
    const int tA = z * 5, tB = tA + 5;   // 20 tiles of 128 keys, 4-way split
    for (int ti = tA; ti < tB; ++ti) {
        const int tile0 = ti * 128;
        if (ti != tA) __syncthreads();
        {
            const short8* kp = (const short8*)(Kbf + (size_t)(tile0 + t) * 128 + head * 16);
            *(short8*)&Ks[t * 24]     = kp[0];
            *(short8*)&Ks[t * 24 + 8] = kp[1];
            const short8* vp = (const short8*)(VTb + (size_t)(head * 16 + vdim) * SEQP2 + tile0 + vseg * 16);
            *(short8*)&Vt[vdim * 136 + vseg * 16]     = vp[0];
            *(short8*)&Vt[vdim * 136 + vseg * 16 + 8] = vp[1];
        }
        __syncthreads();

        f32x4 sA[4], sB[4];
        #pragma unroll
        for (int st = 0; st < 4; ++st) {
            const int k0 = st * 32;
            short8 kfA, kfB;
            #pragma unroll
            for (int i = 0; i < 8; ++i) { kfA[i] = 0; kfB[i] = 0; }
            if (quad < 2) {
                kfA = *(const short8*)&Ks[(k0 + c16) * 24 + quad * 8];
                kfB = *(const short8*)&Ks[(k0 + 16 + c16) * 24 + quad * 8];
            }
            f32x4 zz = {0.f, 0.f, 0.f, 0.f};
            sA[st] = __builtin_amdgcn_mfma_f32_16x16x32_bf16(qf, kfA, zz, 0, 0, 0);
            sB[st] = __builtin_amdgcn_mfma_f32_16x16x32_bf16(qf, kfB, zz, 0, 0, 0);
            const bool badA = (tile0 + k0 + c16) >= SEQ;
            const bool badB = (tile0 + k0 + 16 + c16) >= SEQ;
            if (badA) { sA[st][0] = -1e30f; sA[st][1] = -1e30f; sA[st][2] = -1e30f; sA[st][3] = -1e30f; }
            if (badB) { sB[st][0] = -1e30f; sB[st][1] = -1e30f; sB[st][2] = -1e30f; sB[st][3] = -1e30f; }
        }
        #pragma unroll
        for (int r = 0; r < 4; ++r) {
            float v = fmaxf(sA[0][r], sB[0][r]);
            #pragma unroll
            for (int st = 1; st < 4; ++st) v = fmaxf(v, fmaxf(sA[st][r], sB[st][r]));
            v = fmaxf(v, __shfl_xor(v, 1));
            v = fmaxf(v, __shfl_xor(v, 2));
            v = fmaxf(v, __shfl_xor(v, 4));
            v = fmaxf(v, __shfl_xor(v, 8));
            float nm = fmaxf(m_[r], v);
            float corr = fexp2(m_[r] - nm);
            m_[r] = nm;
            oacc[r] *= corr;
            l_[r] *= corr;
        }
        #pragma unroll
        for (int st = 0; st < 4; ++st) {
            #pragma unroll
            for (int r = 0; r < 4; ++r) {
                float eA = fexp2(sA[st][r] - m_[r]);
                float eB = fexp2(sB[st][r] - m_[r]);
                l_[r] += eA + eB;
                Pw[(quad * 4 + r) * 136 + st * 32 + c16]      = f2bf_trunc(eA);
                Pw[(quad * 4 + r) * 136 + st * 32 + 16 + c16] = f2bf_trunc(eB);
            }
        }
        #pragma unroll
        for (int st = 0; st < 4; ++st) {
            short8 pf = *(const short8*)&Pw[c16 * 136 + st * 32 + quad * 8];
            short8 vf = *(const short8*)&Vt[c16 * 136 + st * 32 + quad * 8];
            oacc = __builtin_amdgcn_mfma_f32_16x16x32_bf16(pf, vf, oacc, 0, 0, 0);
        }
    }
    #pragma unroll
    for (int r = 0; r < 4; ++r) {
        float lr = l_[r];
        lr += __shfl_xor(lr, 1);
        lr += __shfl_xor(lr, 2);
        lr += __shfl_xor(lr, 4);
        lr += __shfl_xor(lr, 8);
        const int qrow = qb + quad * 4 + r;
        if (qrow < SEQ) {
            float* dst = PART + ((size_t)(z * 8 + head) * SEQP + qrow) * 20;
            dst[c16] = oacc[r];
            if (c16 == 0) { dst[16] = m_[r]; dst[17] = lr; }
        }
    }
}

// ---------------- merge the 4 key-split partials and normalize ------------------
__global__ __launch_bounds__(256) void attn_merge_kernel(
    const float* __restrict__ PART, float* __restrict__ O) {
    int idx = blockIdx.x * 256 + threadIdx.x;
    if (idx >= 8 * SEQ * 4) return;
    const int part = idx & 3;
    const int rh = idx >> 2;
    const int head = rh / SEQ;
    const int qrow = rh - head * SEQ;
    const float* p[4];
    float mv[4], lv[4];
    float M = -INFINITY;
    #pragma unroll
    for (int zc = 0; zc < 4; ++zc) {
        p[zc] = PART + ((size_t)(zc * 8 + head) * SEQP + qrow) * 20;
        mv[zc] = p[zc][16]; lv[zc] = p[zc][17];
        M = fmaxf(M, mv[zc]);
    }
    float L = 0.f;
    float w[4];
    #pragma unroll
    for (int zc = 0; zc < 4; ++zc) {
        w[zc] = fexp2(mv[zc] - M);
        L += lv[zc] * w[zc];
    }
    float inv = 1.f / L;
    float4 o = make_float4(0.f, 0.f, 0.f, 0.f);
    #pragma unroll
    for (int zc = 0; zc < 4; ++zc) {
        float4 a = ((const float4*)p[zc])[part];
        o.x = fmaf(a.x, w[zc], o.x); o.y = fmaf(a.y, w[zc], o.y);
        o.z = fmaf(a.z, w[zc], o.z); o.w = fmaf(a.w, w[zc], o.w);
    }
    o.x *= inv; o.y *= inv; o.z *= inv; o.w *= inv;
    ((float4*)&O[(size_t)qrow * 128 + head * 16])[part] = o;
}

// ---- region + map_fuse + channel-LN stats (fused) ------------------------------
__global__ __launch_bounds__(256) void region_fuse_stats_kernel(
    const float* __restrict__ sup, const float* __restrict__ qry,
    const float* __restrict__ X, float* __restrict__ fused,
    float* __restrict__ MEAN, float* __restrict__ RSTD) {
    __shared__ float key0[2048];
    __shared__ float rfac[100];
    const int b = blockIdx.x;
    const int t = threadIdx.x;
    const float* feat = (b < 25) ? (sup + (size_t)b * 12800) : (qry + (size_t)(b - 25) * 12800);
    for (int i = t; i < 2048; i += 256) key0[i] = X[i];
    __syncthreads();
    if (t < 100) {
        float dots[16];
        #pragma unroll
        for (int mm = 0; mm < 16; ++mm) dots[mm] = 0.f;
        float s = 0.f, ss = 0.f;
        for (int c = 0; c < 128; ++c) {
            float f = feat[c * 100 + t];
            s += f; ss += f * f;
            #pragma unroll
            for (int mm = 0; mm < 16; ++mm) dots[mm] += f * key0[mm * 128 + c];
        }
        float mean16 = 0.f;
        #pragma unroll
        for (int mm = 0; mm < 16; ++mm) mean16 += 1.f / (1.f + expf(-dots[mm] * (1.f / 128.f)));
        float r = mean16 * (1.f / 16.f) + 1.f;
        rfac[t] = r;
        float mr = s * (1.f / 128.f);
        float vr = ss * (1.f / 128.f) - mr * mr;
        MEAN[b * 128 + t] = mr * r;
        RSTD[b * 128 + t] = rsqrtf(vr * r * r + 1e-6f);
    }
    __syncthreads();
    for (int i = t; i < 12800; i += 256)
        fused[(size_t)b * 12800 + i] = feat[i] * rfac[i % 100];
}

// ---- conv1 split over input channels: grid (100, 4 to-groups, 4 cin-chunks) ----
__global__ __launch_bounds__(256) void conv1_split_kernel(
    const float* __restrict__ in, const float* __restrict__ w,
    const float* __restrict__ MEAN, const float* __restrict__ RSTD,
    const float* __restrict__ g, const float* __restrict__ bb,
    float* __restrict__ PARTC) {
    __shared__ float sin_[32 * 144];
    const int b = blockIdx.x;
    const int base_to = blockIdx.y * 8;
    const int cb = blockIdx.z * 32;
    const int t = threadIdx.x;
    const int h = __builtin_amdgcn_readfirstlane(t >> 7);
    const int p = t & 127;
    const int py = p / 10, px = p - py * 10;
    const bool active = p < 100;
    float acc[4] = {0.f, 0.f, 0.f, 0.f};
    for (int i = t; i < 32 * 144; i += 256) {
        int c = i / 144, pos = i - c * 144;
        int y = pos / 12 - 1, x = pos % 12 - 1;
        float v = 0.f;
        if ((unsigned)y < 10u && (unsigned)x < 10u) {
            int pp = y * 10 + x;
            float raw = in[(size_t)b * 12800 + (cb + c) * 100 + pp];
            v = (raw - MEAN[b * 128 + pp]) * RSTD[b * 128 + pp] * g[cb + c] + bb[cb + c];
        }
        sin_[i] = v;
    }
    __syncthreads();
    if (active) {
        const float* wbase = w + ((size_t)(base_to + h * 4) * 128 + cb) * 9;
        for (int c = 0; c < 32; ++c) {
            const float* sp = &sin_[c * 144 + py * 12 + px];
            float pix[9];
            #pragma unroll
            for (int k = 0; k < 9; ++k) pix[k] = sp[(k / 3) * 12 + (k % 3)];
            #pragma unroll
            for (int j = 0; j < 4; ++j) {
                const float* wq = wbase + ((size_t)j * 128 + c) * 9;
                #pragma unroll
                for (int k = 0; k < 9; ++k) acc[j] = fmaf(pix[k], wq[k], acc[j]);
            }
        }
        #pragma unroll
        for (int j = 0; j < 4; ++j)
            PARTC[((size_t)blockIdx.z * 100 + b) * 3200 + (base_to + h * 4 + j) * 100 + p] = acc[j];
    }
}

// ------- 3x3 conv (CIN=32), pad 1, grid (100, 8): 2 to-ch per half-block --------
// COMBINE: input is 4 conv1 partial buffers (stride 320000); staging sums + relu.
template<bool RELU, bool COMBINE>
__global__ __launch_bounds__(256) void conv3x3_to4_kernel(
    const float* __restrict__ in, const float* __restrict__ w,
    float* __restrict__ out) {
    __shared__ float sin_[32 * 144];
    const int b = blockIdx.x;
    const int base_to = blockIdx.y * 4;
    const int t = threadIdx.x;
    const int h = __builtin_amdgcn_readfirstlane(t >> 7);
    const int p = t & 127;
    const int py = p / 10, px = p - py * 10;
    const bool active = p < 100;
    float acc[2] = {0.f, 0.f};
    for (int i = t; i < 32 * 144; i += 256) {
        int c = i / 144, pos = i - c * 144;
        int y = pos / 12 - 1, x = pos % 12 - 1;
        float v = 0.f;
        if ((unsigned)y < 10u && (unsigned)x < 10u) {
            if (COMBINE) {
                const size_t base = (size_t)b * 3200 + c * 100 + y * 10 + x;
                v = in[base] + in[base + 320000] + in[base + 640000] + in[base + 960000];
                v = fmaxf(v, 0.f);
            } else {
                v = in[(size_t)b * 3200 + c * 100 + y * 10 + x];
            }
        }
        sin_[i] = v;
    }
    __syncthreads();
    if (active) {
        const float* wbase = w + ((size_t)(base_to + h * 2) * 32) * 9;
        for (int c = 0; c < 32; ++c) {
            const float* sp = &sin_[c * 144 + py * 12 + px];
            float pix[9];
            #pragma unroll
            for (int k = 0; k < 9; ++k) pix[k] = sp[(k / 3) * 12 + (k % 3)];
            #pragma unroll
            for (int j = 0; j < 2; ++j) {
                const float* wq = wbase + ((size_t)j * 32 + c) * 9;
                #pragma unroll
                for (int k = 0; k < 9; ++k) acc[j] = fmaf(pix[k], wq[k], acc[j]);
            }
        }
        #pragma unroll
        for (int j = 0; j < 2; ++j) {
            float v = acc[j];
            if (RELU) v = fmaxf(v, 0.f);
            out[(size_t)b * 3200 + (base_to + h * 2 + j) * 100 + p] = v;
        }
    }
}

// ---------------- final pooling -------------------------------------------------
__global__ __launch_bounds__(256) void rfm_out_kernel(
    const float* __restrict__ conv4, const float* __restrict__ fused, float* __restrict__ out) {
    __shared__ float sig[3200];
    __shared__ float sf[12800];
    const int b = blockIdx.x;
    const int t = threadIdx.x;
    for (int i = t; i < 3200; i += 256) sig[i] = 1.f / (1.f + expf(-conv4[(size_t)b * 3200 + i]));
    for (int i = t; i < 12800; i += 256) sf[i] = fused[(size_t)b * 12800 + i];
    __syncthreads();
    for (int o = t; o < 4096; o += 256) {
        int c = o >> 5, tt = o & 31;
        float acc = 0.f;
        for (int p = 0; p < 100; ++p) acc += sig[tt * 100 + p] * sf[c * 100 + p];
        out[(size_t)b * 4096 + o] = acc * 0.01f;
    }
}

extern "C" void kernel_launch(void* const* d_in, const int* in_sizes, int n_in,
                              void* d_out, int out_size, void* d_ws, size_t ws_size,
                              hipStream_t stream) {
    (void)in_sizes; (void)n_in; (void)out_size; (void)ws_size;
    const float* sup    = (const float*)d_in[0];
    const float* qry    = (const float*)d_in[1];
    const float* td     = (const float*)d_in[2];
    const float* ln1_g  = (const float*)d_in[3];
    const float* ln1_b  = (const float*)d_in[4];
    const float* qkv_w  = (const float*)d_in[5];
    const float* qkv_b  = (const float*)d_in[6];
    const float* out_w  = (const float*)d_in[7];
    const float* out_b  = (const float*)d_in[8];
    const float* ln2_g  = (const float*)d_in[9];
    const float* ln2_b  = (const float*)d_in[10];
    const float* mlp_w1 = (const float*)d_in[11];
    const float* mlp_b1 = (const float*)d_in[12];
    const float* mlp_w2 = (const float*)d_in[13];
    const float* mlp_b2 = (const float*)d_in[14];
    const float* rg     = (const float*)d_in[15];
    const float* rb     = (const float*)d_in[16];
    const float* c1     = (const float*)d_in[17];
    const float* c2     = (const float*)d_in[18];
    const float* c3     = (const float*)d_in[19];
    const float* c4     = (const float*)d_in[20];
    float* out = (float*)d_out;

    float* ws   = (float*)d_ws;
    float* X    = ws;                  // 327680
    float* H    = X + 327680;          // 327680
    float* Obuf = H + 327680;          // 327680
    float* MLPH = Obuf + 327680;       // 1310720 (reused as PARTC)
    float* FUSED= MLPH + 1310720;      // 1280000
    float* MEAN = FUSED + 1280000;     // 12800
    float* RSTD = MEAN + 12800;        // 12800
    float* CB1  = RSTD + 12800;        // 320000
    float* CB2  = CB1 + 320000;        // 320000
    short* Qbf  = (short*)(CB2 + 320000);    // 2560*128 shorts
    short* Kbf  = Qbf + 327680;              // 2560*128 shorts
    short* VTb  = Kbf + 327680;              // 128*2560 shorts
    float* PARTG= (float*)(VTb + 327680);    // 8*2560*128 = 2621440 floats
    // PART (attn split partials, 4*8*2520*20 = 1612800 floats) aliases PARTG:
    // disjoint liveness — PART dies at attn_merge, PARTG born at mlp2 kpart.
    float* PART = PARTG;
    float* PARTC= MLPH;

    const int SG = (SEQ + 7) / 8;      // 315 blocks
    const int MG = (8 * SEQ * 4 + 255) / 256;
    const int MT = (SEQ + 63) / 64;    // 40 M-tiles

    concat_ln_kernel<<<SEQ, 64, 0, stream>>>(td, sup, ln1_g, ln1_b, X, H);
    for (int i = 0; i < 2; ++i) {
        qkv_mfma_kernel<<<dim3(MT, 6), 256, 0, stream>>>(
            H, qkv_w + (size_t)i * 128 * 384, qkv_b + i * 384, Qbf, Kbf, VTb);
        attn_kernel<<<dim3((SEQ + 31) / 32, 8, 4), 128, 0, stream>>>(Qbf, Kbf, VTb, PART);
        attn_merge_kernel<<<MG, 256, 0, stream>>>(PART, Obuf);
        sgemm_ln_kernel<<<SG, 512, 0, stream>>>(
            Obuf, out_w + (size_t)i * 128 * 128, out_b + i * 128, X, X, H,
            ln2_g + i * 128, ln2_b + i * 128, SEQ, 128);
        mfma_gemm_kernel<<<dim3(MT, 8), 256, 0, stream>>>(
            H, mlp_w1 + (size_t)i * 128 * 512, mlp_b1 + i * 512, MLPH, SEQ, 512);
        const float* ng = (i == 0) ? ln1_g + 128 : ln1_g;
        const float* nb = (i == 0) ? ln1_b + 128 : ln1_b;
        mfma_gemm_kpart_kernel<<<dim3(MT, 8), 256, 0, stream>>>(
            MLPH, mlp_w2 + (size_t)i * 512 * 128, PARTG);
        combine_ln_kernel<<<SG, 512, 0, stream>>>(
            PARTG, mlp_b2 + i * 128, X, X, H, ng, nb, SEQ);
    }
    region_fuse_stats_kernel<<<100, 256, 0, stream>>>(sup, qry, X, FUSED, MEAN, RSTD);
    conv1_split_kernel<<<dim3(100, 4, 4), 256, 0, stream>>>(FUSED, c1, MEAN, RSTD, rg, rb, PARTC);
    conv3x3_to4_kernel<true,  true ><<<dim3(100, 8), 256, 0, stream>>>(PARTC, c2, CB2);
    conv3x3_to4_kernel<true,  false><<<dim3(100, 8), 256, 0, stream>>>(CB2, c3, CB1);
    conv3x3_to4_kernel<false, false><<<dim3(100, 8), 256, 0, stream>>>(CB1, c4, CB2);
    rfm_out_kernel<<<100, 256, 0, stream>>>(CB2, FUSED, out);
}

// Round 19
// 340.445 us; speedup vs baseline: 1.0241x; 1.0241x over previous
//
#include <hip/hip_runtime.h>
#include <math.h>

#define SEQ 2516
#define SEQP 2520
#define SEQP2 2560
#define CDIM 128

typedef __attribute__((ext_vector_type(8))) short short8;
typedef __attribute__((ext_vector_type(4))) float f32x4;

__device__ __forceinline__ float gelu_exact(float x) {
    return x * 0.5f * (1.0f + erff(x * 0.7071067811865475f));
}
__device__ __forceinline__ float fexp2(float x) { return __builtin_amdgcn_exp2f(x); }
__device__ __forceinline__ short f2bf(float f) {     // fp32 -> bf16 RNE
    unsigned u = __float_as_uint(f);
    unsigned r = 0x7fffu + ((u >> 16) & 1u);
    return (short)((u + r) >> 16);
}
__device__ __forceinline__ short f2bf_trunc(float f) {   // for P (e>=0): 1 op
    return (short)(__float_as_uint(f) >> 16);
}

// ---------------- concat + LN1(layer0): one wave per row ------------------------
__global__ __launch_bounds__(64) void concat_ln_kernel(
    const float* __restrict__ td, const float* __restrict__ sup,
    const float* __restrict__ g, const float* __restrict__ b,
    float* __restrict__ X, float* __restrict__ H) {
    const int row = blockIdx.x;
    const int t = threadIdx.x;
    float x0, x1;
    if (row < 16) {
        x0 = td[row * 128 + t];
        x1 = td[row * 128 + 64 + t];
    } else {
        int r = row - 16;
        int n = r / 100, p = r - n * 100;
        x0 = sup[n * 12800 + t * 100 + p];
        x1 = sup[n * 12800 + (t + 64) * 100 + p];
    }
    X[row * 128 + t] = x0;
    X[row * 128 + 64 + t] = x1;
    float s = x0 + x1;
    for (int off = 32; off > 0; off >>= 1) s += __shfl_down(s, off);
    float mean = __shfl(s, 0) * (1.f / 128.f);
    float d0 = x0 - mean, d1 = x1 - mean;
    float v = d0 * d0 + d1 * d1;
    for (int off = 32; off > 0; off >>= 1) v += __shfl_down(v, off);
    float var = __shfl(v, 0) * (1.f / 128.f);
    float rstd = rsqrtf(var + 1e-5f);
    H[row * 128 + t]      = d0 * rstd * g[t] + b[t];
    H[row * 128 + 64 + t] = d1 * rstd * g[t + 64] + b[t + 64];
}

// ---- qkv MFMA GEMM: writes Q prescaled bf16, K bf16 rows, V TRANSPOSED bf16 ----
__global__ __launch_bounds__(256) void qkv_mfma_kernel(
    const float* __restrict__ A, const float* __restrict__ W,
    const float* __restrict__ bias,
    short* __restrict__ Qbf, short* __restrict__ Kbf, short* __restrict__ VTb) {
    __shared__ __align__(16) short Wt[64 * 136];   // 17.4 KB
    const int t = threadIdx.x;
    const int wave = t >> 6, lane = t & 63;
    const int quad = lane >> 4, c16 = lane & 15;
    const int m0 = blockIdx.x * 64;
    const int n0 = blockIdx.y * 64;
    const float SC = 0.25f * 1.4426950408889634f;   // folded into Q
    #pragma unroll
    for (int pass = 0; pass < 4; ++pass) {
        int idx = t + pass * 256;
        int n = idx & 63, kc = idx >> 6;
        short8 wv;
        #pragma unroll
        for (int j = 0; j < 8; ++j)
            wv[j] = f2bf(W[(size_t)(kc * 8 + j) * 384 + n0 + n]);
        *(short8*)&Wt[n * 136 + kc * 8] = wv;
    }
    __syncthreads();
    const int am = m0 + wave * 16 + c16;
    f32x4 acc[4];
    #pragma unroll
    for (int i = 0; i < 4; ++i) acc[i] = (f32x4){0.f, 0.f, 0.f, 0.f};
    #pragma unroll
    for (int kk = 0; kk < 4; ++kk) {
        const float4* ap = (const float4*)(A + (size_t)am * 128 + kk * 32 + quad * 8);
        float4 a0 = ap[0], a1 = ap[1];
        short8 af;
        af[0] = f2bf(a0.x); af[1] = f2bf(a0.y); af[2] = f2bf(a0.z); af[3] = f2bf(a0.w);
        af[4] = f2bf(a1.x); af[5] = f2bf(a1.y); af[6] = f2bf(a1.z); af[7] = f2bf(a1.w);
        #pragma unroll
        for (int ns = 0; ns < 4; ++ns) {
            short8 wf = *(const short8*)&Wt[(ns * 16 + c16) * 136 + kk * 32 + quad * 8];
            acc[ns] = __builtin_amdgcn_mfma_f32_16x16x32_bf16(af, wf, acc[ns], 0, 0, 0);
        }
    }
    const int region = __builtin_amdgcn_readfirstlane(n0 >> 7);  // 0 Q, 1 K, 2 V
    #pragma unroll
    for (int ns = 0; ns < 4; ++ns) {
        const int n = n0 + ns * 16 + c16;
        float bv = bias[n];
        #pragma unroll
        for (int r = 0; r < 4; ++r) {
            const int row = m0 + wave * 16 + quad * 4 + r;
            float v = acc[ns][r] + bv;
            if (region == 0)      Qbf[(size_t)row * 128 + n] = f2bf(v * SC);
            else if (region == 1) Kbf[(size_t)row * 128 + (n - 128)] = f2bf(v);
            else                  VTb[(size_t)(n - 256) * SEQP2 + row] = f2bf(v);
        }
    }
}

// -------- MFMA bf16 GEMM (mlp1): C = gelu(A@W + bias) fp32 out ------------------
__global__ __launch_bounds__(256) void mfma_gemm_kernel(
    const float* __restrict__ A, const float* __restrict__ W,
    const float* __restrict__ bias, float* __restrict__ C, int M, int N) {
    __shared__ __align__(16) short Wt[64 * 136];
    const int t = threadIdx.x;
    const int wave = t >> 6, lane = t & 63;
    const int quad = lane >> 4, c16 = lane & 15;
    const int m0 = blockIdx.x * 64;
    const int n0 = blockIdx.y * 64;
    #pragma unroll
    for (int pass = 0; pass < 4; ++pass) {
        int idx = t + pass * 256;
        int n = idx & 63, kc = idx >> 6;
        short8 wv;
        #pragma unroll
        for (int j = 0; j < 8; ++j)
            wv[j] = f2bf(W[(size_t)(kc * 8 + j) * N + n0 + n]);
        *(short8*)&Wt[n * 136 + kc * 8] = wv;
    }
    __syncthreads();
    const int am = m0 + wave * 16 + c16;
    f32x4 acc[4];
    #pragma unroll
    for (int i = 0; i < 4; ++i) acc[i] = (f32x4){0.f, 0.f, 0.f, 0.f};
    #pragma unroll
    for (int kk = 0; kk < 4; ++kk) {
        const float4* ap = (const float4*)(A + (size_t)am * 128 + kk * 32 + quad * 8);
        float4 a0 = ap[0], a1 = ap[1];
        short8 af;
        af[0] = f2bf(a0.x); af[1] = f2bf(a0.y); af[2] = f2bf(a0.z); af[3] = f2bf(a0.w);
        af[4] = f2bf(a1.x); af[5] = f2bf(a1.y); af[6] = f2bf(a1.z); af[7] = f2bf(a1.w);
        #pragma unroll
        for (int ns = 0; ns < 4; ++ns) {
            short8 wf = *(const short8*)&Wt[(ns * 16 + c16) * 136 + kk * 32 + quad * 8];
            acc[ns] = __builtin_amdgcn_mfma_f32_16x16x32_bf16(af, wf, acc[ns], 0, 0, 0);
        }
    }
    #pragma unroll
    for (int ns = 0; ns < 4; ++ns) {
        const int n = n0 + ns * 16 + c16;
        float bv = bias[n];
        #pragma unroll
        for (int r = 0; r < 4; ++r) {
            int row = m0 + wave * 16 + quad * 4 + r;
            if (row < M) {
                float v = gelu_exact(acc[ns][r] + bv);
                C[(size_t)row * N + n] = v;
            }
        }
    }
}

// ---- mlp2 MFMA with K-split: grid (40 M-tiles, 8 K-splits of 64) ---------------
__global__ __launch_bounds__(256) void mfma_gemm_kpart_kernel(
    const float* __restrict__ A, const float* __restrict__ W,
    float* __restrict__ PARTG) {
    __shared__ __align__(16) short Wt[128 * 72];   // 18.4 KB
    const int t = threadIdx.x;
    const int wave = t >> 6, lane = t & 63;
    const int quad = lane >> 4, c16 = lane & 15;
    const int m0 = blockIdx.x * 64;
    const int kz = blockIdx.y;
    const int kbase = kz * 64;
    {
        const int n = t & 127, half = t >> 7;
        #pragma unroll
        for (int c = 0; c < 4; ++c) {
            short8 wv;
            #pragma unroll
            for (int j = 0; j < 8; ++j)
                wv[j] = f2bf(W[(size_t)(kbase + half * 32 + c * 8 + j) * 128 + n]);
            *(short8*)&Wt[n * 72 + half * 32 + c * 8] = wv;
        }
    }
    __syncthreads();
    const int am = m0 + wave * 16 + c16;
    f32x4 acc[8];
    #pragma unroll
    for (int i = 0; i < 8; ++i) acc[i] = (f32x4){0.f, 0.f, 0.f, 0.f};
    #pragma unroll
    for (int kk = 0; kk < 2; ++kk) {
        const float4* ap = (const float4*)(A + (size_t)am * 512 + kbase + kk * 32 + quad * 8);
        float4 a0 = ap[0], a1 = ap[1];
        short8 af;
        af[0] = f2bf(a0.x); af[1] = f2bf(a0.y); af[2] = f2bf(a0.z); af[3] = f2bf(a0.w);
        af[4] = f2bf(a1.x); af[5] = f2bf(a1.y); af[6] = f2bf(a1.z); af[7] = f2bf(a1.w);
        #pragma unroll
        for (int ns = 0; ns < 8; ++ns) {
            short8 wf = *(const short8*)&Wt[(ns * 16 + c16) * 72 + kk * 32 + quad * 8];
            acc[ns] = __builtin_amdgcn_mfma_f32_16x16x32_bf16(af, wf, acc[ns], 0, 0, 0);
        }
    }
    float* dst = PARTG + (size_t)kz * SEQP2 * 128;
    #pragma unroll
    for (int ns = 0; ns < 8; ++ns) {
        #pragma unroll
        for (int r = 0; r < 4; ++r) {
            const int row = m0 + wave * 16 + quad * 4 + r;
            dst[(size_t)row * 128 + ns * 16 + c16] = acc[ns][r];
        }
    }
}

// ---- combine 8 K-split partials + bias + residual + row-LN ---------------------
__global__ __launch_bounds__(512) void combine_ln_kernel(
    const float* __restrict__ PARTG, const float* __restrict__ bias,
    const float* __restrict__ R, float* __restrict__ C, float* __restrict__ H,
    const float* __restrict__ g, const float* __restrict__ bb, int M) {
    __shared__ float ln[8][130];
    const int t = threadIdx.x;
    const int c = t & 127;
    const int grp = __builtin_amdgcn_readfirstlane(t >> 7);
    const int r0 = blockIdx.x * 8 + grp * 2;
    #pragma unroll
    for (int i = 0; i < 2; ++i) {
        const int row = r0 + i;
        float v = bias[c] + R[(size_t)row * 128 + c];
        #pragma unroll
        for (int kz = 0; kz < 8; ++kz)
            v += PARTG[(size_t)kz * SEQP2 * 128 + (size_t)row * 128 + c];
        ln[grp * 2 + i][c] = v;
        if (row < M) C[(size_t)row * 128 + c] = v;
    }
    __syncthreads();
    const int wv = t >> 6, l = t & 63;
    float x0 = ln[wv][l], x1 = ln[wv][l + 64];
    float s = x0 + x1;
    for (int off = 32; off > 0; off >>= 1) s += __shfl_down(s, off);
    float mean = __shfl(s, 0) * (1.f / 128.f);
    float d0 = x0 - mean, d1 = x1 - mean;
    float vv = d0 * d0 + d1 * d1;
    for (int off = 32; off > 0; off >>= 1) vv += __shfl_down(vv, off);
    float var = __shfl(vv, 0) * (1.f / 128.f);
    float rstd = rsqrtf(var + 1e-5f);
    const int hrow = blockIdx.x * 8 + wv;
    H[(size_t)hrow * 128 + l]      = d0 * rstd * g[l] + bb[l];
    H[(size_t)hrow * 128 + 64 + l] = d1 * rstd * g[l + 64] + bb[l + 64];
}

// ---- proj GEMM fused with attn 2-way split merge + residual + row-LN -----------
// A operand = 2 unnormalized attention partials (PART layout
// ((z*8+h)*SEQP+row)*20 : acc[16], m, l). Per row-pair (wave-uniform) the
// per-head combine coefficients are computed once; A element = P0*c0 + P1*c1.
__global__ __launch_bounds__(512) void proj_merge_ln_kernel(
    const float* __restrict__ PART, const float* __restrict__ W,
    const float* __restrict__ bias, const float* __restrict__ R,
    float* __restrict__ C, float* __restrict__ H,
    const float* __restrict__ g, const float* __restrict__ bb, int M) {
    __shared__ float ln[8][130];
    const int t = threadIdx.x;
    const int c = t & 127;
    const int grp = __builtin_amdgcn_readfirstlane(t >> 7);
    const int r0 = blockIdx.x * 8 + grp * 2;
    float acc0 = 0.f, acc1 = 0.f;
    #pragma unroll
    for (int h = 0; h < 8; ++h) {
        const float* p0a = PART + ((size_t)h * SEQP + r0) * 20;        // z0, row0
        const float* p1a = PART + ((size_t)(8 + h) * SEQP + r0) * 20;  // z1, row0
        const float* p0b = p0a + 20;                                   // row1
        const float* p1b = p1a + 20;
        float m0 = p0a[16], l0 = p0a[17], m1 = p1a[16], l1 = p1a[17];
        float Ma = fmaxf(m0, m1);
        float w0 = fexp2(m0 - Ma), w1 = fexp2(m1 - Ma);
        float inva = 1.f / fmaf(l0, w0, l1 * w1);
        float c0a = w0 * inva, c1a = w1 * inva;
        m0 = p0b[16]; l0 = p0b[17]; m1 = p1b[16]; l1 = p1b[17];
        float Mb = fmaxf(m0, m1);
        w0 = fexp2(m0 - Mb); w1 = fexp2(m1 - Mb);
        float invb = 1.f / fmaf(l0, w0, l1 * w1);
        float c0b = w0 * invb, c1b = w1 * invb;
        #pragma unroll
        for (int kk = 0; kk < 4; ++kk) {
            const int k0 = h * 16 + kk * 4;
            float w_0 = W[(size_t)(k0 + 0) * 128 + c];
            float w_1 = W[(size_t)(k0 + 1) * 128 + c];
            float w_2 = W[(size_t)(k0 + 2) * 128 + c];
            float w_3 = W[(size_t)(k0 + 3) * 128 + c];
            float4 x0 = *(const float4*)&p0a[kk * 4];
            float4 y0 = *(const float4*)&p1a[kk * 4];
            float4 x1 = *(const float4*)&p0b[kk * 4];
            float4 y1 = *(const float4*)&p1b[kk * 4];
            float a00 = x0.x * c0a + y0.x * c1a;
            float a01 = x0.y * c0a + y0.y * c1a;
            float a02 = x0.z * c0a + y0.z * c1a;
            float a03 = x0.w * c0a + y0.w * c1a;
            float a10 = x1.x * c0b + y1.x * c1b;
            float a11 = x1.y * c0b + y1.y * c1b;
            float a12 = x1.z * c0b + y1.z * c1b;
            float a13 = x1.w * c0b + y1.w * c1b;
            acc0 = fmaf(a00, w_0, acc0); acc0 = fmaf(a01, w_1, acc0);
            acc0 = fmaf(a02, w_2, acc0); acc0 = fmaf(a03, w_3, acc0);
            acc1 = fmaf(a10, w_0, acc1); acc1 = fmaf(a11, w_1, acc1);
            acc1 = fmaf(a12, w_2, acc1); acc1 = fmaf(a13, w_3, acc1);
        }
    }
    float bv = bias[c];
    float v0 = acc0 + bv + R[(size_t)(r0 + 0) * 128 + c];
    float v1 = acc1 + bv + R[(size_t)(r0 + 1) * 128 + c];
    ln[grp * 2 + 0][c] = v0;
    ln[grp * 2 + 1][c] = v1;
    if (r0 + 0 < M) C[(size_t)(r0 + 0) * 128 + c] = v0;
    if (r0 + 1 < M) C[(size_t)(r0 + 1) * 128 + c] = v1;
    __syncthreads();
    const int wv = t >> 6, l = t & 63;
    float x0 = ln[wv][l], x1 = ln[wv][l + 64];
    float s = x0 + x1;
    for (int off = 32; off > 0; off >>= 1) s += __shfl_down(s, off);
    float mean = __shfl(s, 0) * (1.f / 128.f);
    float d0 = x0 - mean, d1 = x1 - mean;
    float vv = d0 * d0 + d1 * d1;
    for (int off = 32; off > 0; off >>= 1) vv += __shfl_down(vv, off);
    float var = __shfl(vv, 0) * (1.f / 128.f);
    float rstd = rsqrtf(var + 1e-5f);
    const int hrow = blockIdx.x * 8 + wv;
    H[(size_t)hrow * 128 + l]      = d0 * rstd * g[l] + bb[l];
    H[(size_t)hrow * 128 + 64 + l] = d1 * rstd * g[l + 64] + bb[l + 64];
}

// ---- attention: bf16 MFMA flash, pre-converted inputs, split-K=2 ---------------
__global__ __launch_bounds__(128) void attn_kernel(
    const short* __restrict__ Qbf, const short* __restrict__ Kbf,
    const short* __restrict__ VTb, float* __restrict__ PART) {
    __shared__ __align__(16) short sKs[9600];  // Ks 128*24 | Vt 16*136 | P 2*16*136
    short* Ks = sKs;
    short* Vt = sKs + 3072;
    const int t = threadIdx.x;
    const int wave = t >> 6, lane = t & 63;
    const int quad = lane >> 4, c16 = lane & 15;
    short* Pw = sKs + 3072 + 2176 + wave * 16 * 136;
    const int head = blockIdx.y, z = blockIdx.z;
    const int qb = blockIdx.x * 32 + wave * 16;

    short8 qf;
    #pragma unroll
    for (int i = 0; i < 8; ++i) qf[i] = 0;
    if (quad < 2)
        qf = *(const short8*)(Qbf + (size_t)(qb + c16) * 128 + head * 16 + quad * 8);
    f32x4 oacc = {0.f, 0.f, 0.f, 0.f};
    float m_[4] = {-INFINITY, -INFINITY, -INFINITY, -INFINITY};
    float l_[4] = {0.f, 0.f, 0.f, 0.f};

    const int vdim = t >> 3, vseg = t & 7;
    const int tA = z * 10, tB = z ? 20 : 10;   // 20 tiles of 128 keys, 2-way split
    for (int ti = tA; ti < tB; ++ti) {
        const int tile0 = ti * 128;
        if (ti != tA) __syncthreads();
        {
            const short8* kp = (const short8*)(Kbf + (size_t)(tile0 + t) * 128 + head * 16);
            *(short8*)&Ks[t * 24]     = kp[0];
            *(short8*)&Ks[t * 24 + 8] = kp[1];
            const short8* vp = (const short8*)(VTb + (size_t)(head * 16 + vdim) * SEQP2 + tile0 + vseg * 16);
            *(short8*)&Vt[vdim * 136 + vseg * 16]     = vp[0];
            *(short8*)&Vt[vdim * 136 + vseg * 16 + 8] = vp[1];
        }
        __syncthreads();

        f32x4 sA[4], sB[4];
        #pragma unroll
        for (int st = 0; st < 4; ++st) {
            const int k0 = st * 32;
            short8 kfA, kfB;
            #pragma unroll
            for (int i = 0; i < 8; ++i) { kfA[i] = 0; kfB[i] = 0; }
            if (quad < 2) {
                kfA = *(const short8*)&Ks[(k0 + c16) * 24 + quad * 8];
                kfB = *(const short8*)&Ks[(k0 + 16 + c16) * 24 + quad * 8];
            }
            f32x4 zz = {0.f, 0.f, 0.f, 0.f};
            sA[st] = __builtin_amdgcn_mfma_f32_16x16x32_bf16(qf, kfA, zz, 0, 0, 0);
            sB[st] = __builtin_amdgcn_mfma_f32_16x16x32_bf16(qf, kfB, zz, 0, 0, 0);
            const bool badA = (tile0 + k0 + c16) >= SEQ;
            const bool badB = (tile0 + k0 + 16 + c16) >= SEQ;
            if (badA) { sA[st][0] = -1e30f; sA[st][1] = -1e30f; sA[st][2] = -1e30f; sA[st][3] = -1e30f; }
            if (badB) { sB[st][0] = -1e30f; sB[st][1] = -1e30f; sB[st][2] = -1e30f; sB[st][3] = -1e30f; }
        }
        #pragma unroll
        for (int r = 0; r < 4; ++r) {
            float v = fmaxf(sA[0][r], sB[0][r]);
            #pragma unroll
            for (int st = 1; st < 4; ++st) v = fmaxf(v, fmaxf(sA[st][r], sB[st][r]));
            v = fmaxf(v, __shfl_xor(v, 1));
            v = fmaxf(v, __shfl_xor(v, 2));
            v = fmaxf(v, __shfl_xor(v, 4));
            v = fmaxf(v, __shfl_xor(v, 8));
            float nm = fmaxf(m_[r], v);
            float corr = fexp2(m_[r] - nm);
            m_[r] = nm;
            oacc[r] *= corr;
            l_[r] *= corr;
        }
        #pragma unroll
        for (int st = 0; st < 4; ++st) {
            #pragma unroll
            for (int r = 0; r < 4; ++r) {
                float eA = fexp2(sA[st][r] - m_[r]);
                float eB = fexp2(sB[st][r] - m_[r]);
                l_[r] += eA + eB;
                Pw[(quad * 4 + r) * 136 + st * 32 + c16]      = f2bf_trunc(eA);
                Pw[(quad * 4 + r) * 136 + st * 32 + 16 + c16] = f2bf_trunc(eB);
            }
        }
        #pragma unroll
        for (int st = 0; st < 4; ++st) {
            short8 pf = *(const short8*)&Pw[c16 * 136 + st * 32 + quad * 8];
            short8 vf = *(const short8*)&Vt[c16 * 136 + st * 32 + quad * 8];
            oacc = __builtin_amdgcn_mfma_f32_16x16x32_bf16(pf, vf, oacc, 0, 0, 0);
        }
    }
    #pragma unroll
    for (int r = 0; r < 4; ++r) {
        float lr = l_[r];
        lr += __shfl_xor(lr, 1);
        lr += __shfl_xor(lr, 2);
        lr += __shfl_xor(lr, 4);
        lr += __shfl_xor(lr, 8);
        const int qrow = qb + quad * 4 + r;
        if (qrow < SEQ) {
            float* dst = PART + ((size_t)(z * 8 + head) * SEQP + qrow) * 20;
            dst[c16] = oacc[r];
            if (c16 == 0) { dst[16] = m_[r]; dst[17] = lr; }
        }
    }
}

// ---- region + map_fuse + channel-LN stats (fused) ------------------------------
__global__ __launch_bounds__(256) void region_fuse_stats_kernel(
    const float* __restrict__ sup, const float* __restrict__ qry,
    const float* __restrict__ X, float* __restrict__ fused,
    float* __restrict__ MEAN, float* __restrict__ RSTD) {
    __shared__ float key0[2048];
    __shared__ float rfac[100];
    const int b = blockIdx.x;
    const int t = threadIdx.x;
    const float* feat = (b < 25) ? (sup + (size_t)b * 12800) : (qry + (size_t)(b - 25) * 12800);
    for (int i = t; i < 2048; i += 256) key0[i] = X[i];
    __syncthreads();
    if (t < 100) {
        float dots[16];
        #pragma unroll
        for (int mm = 0; mm < 16; ++mm) dots[mm] = 0.f;
        float s = 0.f, ss = 0.f;
        for (int c = 0; c < 128; ++c) {
            float f = feat[c * 100 + t];
            s += f; ss += f * f;
            #pragma unroll
            for (int mm = 0; mm < 16; ++mm) dots[mm] += f * key0[mm * 128 + c];
        }
        float mean16 = 0.f;
        #pragma unroll
        for (int mm = 0; mm < 16; ++mm) mean16 += 1.f / (1.f + expf(-dots[mm] * (1.f / 128.f)));
        float r = mean16 * (1.f / 16.f) + 1.f;
        rfac[t] = r;
        float mr = s * (1.f / 128.f);
        float vr = ss * (1.f / 128.f) - mr * mr;
        MEAN[b * 128 + t] = mr * r;
        RSTD[b * 128 + t] = rsqrtf(vr * r * r + 1e-6f);
    }
    __syncthreads();
    for (int i = t; i < 12800; i += 256)
        fused[(size_t)b * 12800 + i] = feat[i] * rfac[i % 100];
}

// ---- conv1 split over input channels: grid (100, 4 to-groups, 4 cin-chunks) ----
__global__ __launch_bounds__(256) void conv1_split_kernel(
    const float* __restrict__ in, const float* __restrict__ w,
    const float* __restrict__ MEAN, const float* __restrict__ RSTD,
    const float* __restrict__ g, const float* __restrict__ bb,
    float* __restrict__ PARTC) {
    __shared__ float sin_[32 * 144];
    const int b = blockIdx.x;
    const int base_to = blockIdx.y * 8;
    const int cb = blockIdx.z * 32;
    const int t = threadIdx.x;
    const int h = __builtin_amdgcn_readfirstlane(t >> 7);
    const int p = t & 127;
    const int py = p / 10, px = p - py * 10;
    const bool active = p < 100;
    float acc[4] = {0.f, 0.f, 0.f, 0.f};
    for (int i = t; i < 32 * 144; i += 256) {
        int c = i / 144, pos = i - c * 144;
        int y = pos / 12 - 1, x = pos % 12 - 1;
        float v = 0.f;
        if ((unsigned)y < 10u && (unsigned)x < 10u) {
            int pp = y * 10 + x;
            float raw = in[(size_t)b * 12800 + (cb + c) * 100 + pp];
            v = (raw - MEAN[b * 128 + pp]) * RSTD[b * 128 + pp] * g[cb + c] + bb[cb + c];
        }
        sin_[i] = v;
    }
    __syncthreads();
    if (active) {
        const float* wbase = w + ((size_t)(base_to + h * 4) * 128 + cb) * 9;
        for (int c = 0; c < 32; ++c) {
            const float* sp = &sin_[c * 144 + py * 12 + px];
            float pix[9];
            #pragma unroll
            for (int k = 0; k < 9; ++k) pix[k] = sp[(k / 3) * 12 + (k % 3)];
            #pragma unroll
            for (int j = 0; j < 4; ++j) {
                const float* wq = wbase + ((size_t)j * 128 + c) * 9;
                #pragma unroll
                for (int k = 0; k < 9; ++k) acc[j] = fmaf(pix[k], wq[k], acc[j]);
            }
        }
        #pragma unroll
        for (int j = 0; j < 4; ++j)
            PARTC[((size_t)blockIdx.z * 100 + b) * 3200 + (base_to + h * 4 + j) * 100 + p] = acc[j];
    }
}

// ------- 3x3 conv (CIN=32), pad 1, grid (100, 8): 2 to-ch per half-block --------
// COMBINE: input is 4 conv1 partial buffers (stride 320000); staging sums + relu.
template<bool RELU, bool COMBINE>
__global__ __launch_bounds__(256) void conv3x3_to4_kernel(
    const float* __restrict__ in, const float* __restrict__ w,
    float* __restrict__ out) {
    __shared__ float sin_[32 * 144];
    const int b = blockIdx.x;
    const int base_to = blockIdx.y * 4;
    const int t = threadIdx.x;
    const int h = __builtin_amdgcn_readfirstlane(t >> 7);
    const int p = t & 127;
    const int py = p / 10, px = p - py * 10;
    const bool active = p < 100;
    float acc[2] = {0.f, 0.f};
    for (int i = t; i < 32 * 144; i += 256) {
        int c = i / 144, pos = i - c * 144;
        int y = pos / 12 - 1, x = pos % 12 - 1;
        float v = 0.f;
        if ((unsigned)y < 10u && (unsigned)x < 10u) {
            if (COMBINE) {
                const size_t base = (size_t)b * 3200 + c * 100 + y * 10 + x;
                v = in[base] + in[base + 320000] + in[base + 640000] + in[base + 960000];
                v = fmaxf(v, 0.f);
            } else {
                v = in[(size_t)b * 3200 + c * 100 + y * 10 + x];
            }
        }
        sin_[i] = v;
    }
    __syncthreads();
    if (active) {
        const float* wbase = w + ((size_t)(base_to + h * 2) * 32) * 9;
        for (int c = 0; c < 32; ++c) {
            const float* sp = &sin_[c * 144 + py * 12 + px];
            float pix[9];
            #pragma unroll
            for (int k = 0; k < 9; ++k) pix[k] = sp[(k / 3) * 12 + (k % 3)];
            #pragma unroll
            for (int j = 0; j < 2; ++j) {
                const float* wq = wbase + ((size_t)j * 32 + c) * 9;
                #pragma unroll
                for (int k = 0; k < 9; ++k) acc[j] = fmaf(pix[k], wq[k], acc[j]);
            }
        }
        #pragma unroll
        for (int j = 0; j < 2; ++j) {
            float v = acc[j];
            if (RELU) v = fmaxf(v, 0.f);
            out[(size_t)b * 3200 + (base_to + h * 2 + j) * 100 + p] = v;
        }
    }
}

// ---- conv4 fused with sigmoid-weighted pooling (rfm output) --------------------
// grid (100, 8): block owns sigmoid rows tt in [4y, 4y+4); after the conv it
// computes out[b, all 128 c, its 4 tt] directly (fused is L2-hot across the
// image's 8 blocks).
__global__ __launch_bounds__(256) void conv4_rfm_kernel(
    const float* __restrict__ in, const float* __restrict__ w,
    const float* __restrict__ fused, float* __restrict__ out) {
    __shared__ float sin_[32 * 144];
    __shared__ float sig[4][104];
    const int b = blockIdx.x;
    const int base_to = blockIdx.y * 4;
    const int t = threadIdx.x;
    const int h = __builtin_amdgcn_readfirstlane(t >> 7);
    const int p = t & 127;
    const int py = p / 10, px = p - py * 10;
    const bool active = p < 100;
    float acc[2] = {0.f, 0.f};
    for (int i = t; i < 32 * 144; i += 256) {
        int c = i / 144, pos = i - c * 144;
        int y = pos / 12 - 1, x = pos % 12 - 1;
        float v = 0.f;
        if ((unsigned)y < 10u && (unsigned)x < 10u)
            v = in[(size_t)b * 3200 + c * 100 + y * 10 + x];
        sin_[i] = v;
    }
    __syncthreads();
    if (active) {
        const float* wbase = w + ((size_t)(base_to + h * 2) * 32) * 9;
        for (int c = 0; c < 32; ++c) {
            const float* sp = &sin_[c * 144 + py * 12 + px];
            float pix[9];
            #pragma unroll
            for (int k = 0; k < 9; ++k) pix[k] = sp[(k / 3) * 12 + (k % 3)];
            #pragma unroll
            for (int j = 0; j < 2; ++j) {
                const float* wq = wbase + ((size_t)j * 32 + c) * 9;
                #pragma unroll
                for (int k = 0; k < 9; ++k) acc[j] = fmaf(pix[k], wq[k], acc[j]);
            }
        }
        sig[h * 2 + 0][p] = 1.f / (1.f + expf(-acc[0]));
        sig[h * 2 + 1][p] = 1.f / (1.f + expf(-acc[1]));
    }
    __syncthreads();
    // pooling: 512 outputs (128 c x 4 ttl); thread handles o = t and t + 256
    #pragma unroll
    for (int rep = 0; rep < 2; ++rep) {
        const int o = t + rep * 256;
        const int cc = o >> 2, ttl = o & 3;
        const float* fp = fused + (size_t)b * 12800 + cc * 100;
        float s = 0.f;
        for (int pp = 0; pp < 100; pp += 4) {
            float4 f4 = *(const float4*)&fp[pp];
            s += sig[ttl][pp] * f4.x + sig[ttl][pp + 1] * f4.y
               + sig[ttl][pp + 2] * f4.z + sig[ttl][pp + 3] * f4.w;
        }
        out[(size_t)b * 4096 + cc * 32 + base_to + ttl] = s * 0.01f;
    }
}

extern "C" void kernel_launch(void* const* d_in, const int* in_sizes, int n_in,
                              void* d_out, int out_size, void* d_ws, size_t ws_size,
                              hipStream_t stream) {
    (void)in_sizes; (void)n_in; (void)out_size; (void)ws_size;
    const float* sup    = (const float*)d_in[0];
    const float* qry    = (const float*)d_in[1];
    const float* td     = (const float*)d_in[2];
    const float* ln1_g  = (const float*)d_in[3];
    const float* ln1_b  = (const float*)d_in[4];
    const float* qkv_w  = (const float*)d_in[5];
    const float* qkv_b  = (const float*)d_in[6];
    const float* out_w  = (const float*)d_in[7];
    const float* out_b  = (const float*)d_in[8];
    const float* ln2_g  = (const float*)d_in[9];
    const float* ln2_b  = (const float*)d_in[10];
    const float* mlp_w1 = (const float*)d_in[11];
    const float* mlp_b1 = (const float*)d_in[12];
    const float* mlp_w2 = (const float*)d_in[13];
    const float* mlp_b2 = (const float*)d_in[14];
    const float* rg     = (const float*)d_in[15];
    const float* rb     = (const float*)d_in[16];
    const float* c1     = (const float*)d_in[17];
    const float* c2     = (const float*)d_in[18];
    const float* c3     = (const float*)d_in[19];
    const float* c4     = (const float*)d_in[20];
    float* out = (float*)d_out;

    float* ws   = (float*)d_ws;
    float* X    = ws;                  // 327680
    float* H    = X + 327680;          // 327680
    float* MLPH = H + 327680;          // 1310720 (reused as PARTC)
    float* FUSED= MLPH + 1310720;      // 1280000
    float* MEAN = FUSED + 1280000;     // 12800
    float* RSTD = MEAN + 12800;        // 12800
    float* CB1  = RSTD + 12800;        // 320000
    float* CB2  = CB1 + 320000;        // 320000
    short* Qbf  = (short*)(CB2 + 320000);    // 2560*128 shorts
    short* Kbf  = Qbf + 327680;              // 2560*128 shorts
    short* VTb  = Kbf + 327680;              // 128*2560 shorts
    float* PARTG= (float*)(VTb + 327680);    // 8*2560*128 floats
    // PART (attn split partials, 2*8*2520*20 = 806400 floats) aliases PARTG:
    // PART dies inside proj_merge, PARTG born at mlp2 kpart.
    float* PART = PARTG;
    float* PARTC= MLPH;

    const int SG = (SEQ + 7) / 8;      // 315 blocks
    const int MT = (SEQ + 63) / 64;    // 40 M-tiles

    concat_ln_kernel<<<SEQ, 64, 0, stream>>>(td, sup, ln1_g, ln1_b, X, H);
    for (int i = 0; i < 2; ++i) {
        qkv_mfma_kernel<<<dim3(MT, 6), 256, 0, stream>>>(
            H, qkv_w + (size_t)i * 128 * 384, qkv_b + i * 384, Qbf, Kbf, VTb);
        attn_kernel<<<dim3((SEQ + 31) / 32, 8, 2), 128, 0, stream>>>(Qbf, Kbf, VTb, PART);
        proj_merge_ln_kernel<<<SG, 512, 0, stream>>>(
            PART, out_w + (size_t)i * 128 * 128, out_b + i * 128, X, X, H,
            ln2_g + i * 128, ln2_b + i * 128, SEQ);
        mfma_gemm_kernel<<<dim3(MT, 8), 256, 0, stream>>>(
            H, mlp_w1 + (size_t)i * 128 * 512, mlp_b1 + i * 512, MLPH, SEQ, 512);
        const float* ng = (i == 0) ? ln1_g + 128 : ln1_g;
        const float* nb = (i == 0) ? ln1_b + 128 : ln1_b;
        mfma_gemm_kpart_kernel<<<dim3(MT, 8), 256, 0, stream>>>(
            MLPH, mlp_w2 + (size_t)i * 512 * 128, PARTG);
        combine_ln_kernel<<<SG, 512, 0, stream>>>(
            PARTG, mlp_b2 + i * 128, X, X, H, ng, nb, SEQ);
    }
    region_fuse_stats_kernel<<<100, 256, 0, stream>>>(sup, qry, X, FUSED, MEAN, RSTD);
    conv1_split_kernel<<<dim3(100, 4, 4), 256, 0, stream>>>(FUSED, c1, MEAN, RSTD, rg, rb, PARTC);
    conv3x3_to4_kernel<true,  true ><<<dim3(100, 8), 256, 0, stream>>>(PARTC, c2, CB2);
    conv3x3_to4_kernel<true,  false><<<dim3(100, 8), 256, 0, stream>>>(CB2, c3, CB1);
    conv4_rfm_kernel<<<dim3(100, 8), 256, 0, stream>>>(CB1, c4, FUSED, out);
}

// Round 20
// 332.325 us; speedup vs baseline: 1.0491x; 1.0244x over previous
//
#include <hip/hip_runtime.h>
#include <math.h>

#define SEQ 2516
#define SEQP 2520
#define SEQP2 2560
#define CDIM 128

typedef __attribute__((ext_vector_type(8))) short short8;
typedef __attribute__((ext_vector_type(4))) float f32x4;

__device__ __forceinline__ float gelu_exact(float x) {
    return x * 0.5f * (1.0f + erff(x * 0.7071067811865475f));
}
__device__ __forceinline__ float fexp2(float x) { return __builtin_amdgcn_exp2f(x); }
__device__ __forceinline__ short f2bf(float f) {     // fp32 -> bf16 RNE
    unsigned u = __float_as_uint(f);
    unsigned r = 0x7fffu + ((u >> 16) & 1u);
    return (short)((u + r) >> 16);
}
__device__ __forceinline__ short f2bf_trunc(float f) {   // for P (e>=0): 1 op
    return (short)(__float_as_uint(f) >> 16);
}

// ---------------- concat + LN1(layer0): one wave per row ------------------------
__global__ __launch_bounds__(64) void concat_ln_kernel(
    const float* __restrict__ td, const float* __restrict__ sup,
    const float* __restrict__ g, const float* __restrict__ b,
    float* __restrict__ X, float* __restrict__ H) {
    const int row = blockIdx.x;
    const int t = threadIdx.x;
    float x0, x1;
    if (row < 16) {
        x0 = td[row * 128 + t];
        x1 = td[row * 128 + 64 + t];
    } else {
        int r = row - 16;
        int n = r / 100, p = r - n * 100;
        x0 = sup[n * 12800 + t * 100 + p];
        x1 = sup[n * 12800 + (t + 64) * 100 + p];
    }
    X[row * 128 + t] = x0;
    X[row * 128 + 64 + t] = x1;
    float s = x0 + x1;
    for (int off = 32; off > 0; off >>= 1) s += __shfl_down(s, off);
    float mean = __shfl(s, 0) * (1.f / 128.f);
    float d0 = x0 - mean, d1 = x1 - mean;
    float v = d0 * d0 + d1 * d1;
    for (int off = 32; off > 0; off >>= 1) v += __shfl_down(v, off);
    float var = __shfl(v, 0) * (1.f / 128.f);
    float rstd = rsqrtf(var + 1e-5f);
    H[row * 128 + t]      = d0 * rstd * g[t] + b[t];
    H[row * 128 + 64 + t] = d1 * rstd * g[t + 64] + b[t + 64];
}

// ---- qkv MFMA GEMM: writes Q prescaled bf16, K bf16 rows, V TRANSPOSED bf16 ----
__global__ __launch_bounds__(256) void qkv_mfma_kernel(
    const float* __restrict__ A, const float* __restrict__ W,
    const float* __restrict__ bias,
    short* __restrict__ Qbf, short* __restrict__ Kbf, short* __restrict__ VTb) {
    __shared__ __align__(16) short Wt[64 * 136];   // 17.4 KB
    const int t = threadIdx.x;
    const int wave = t >> 6, lane = t & 63;
    const int quad = lane >> 4, c16 = lane & 15;
    const int m0 = blockIdx.x * 64;
    const int n0 = blockIdx.y * 64;
    const float SC = 0.25f * 1.4426950408889634f;   // folded into Q
    #pragma unroll
    for (int pass = 0; pass < 4; ++pass) {
        int idx = t + pass * 256;
        int n = idx & 63, kc = idx >> 6;
        short8 wv;
        #pragma unroll
        for (int j = 0; j < 8; ++j)
            wv[j] = f2bf(W[(size_t)(kc * 8 + j) * 384 + n0 + n]);
        *(short8*)&Wt[n * 136 + kc * 8] = wv;
    }
    __syncthreads();
    const int am = m0 + wave * 16 + c16;
    f32x4 acc[4];
    #pragma unroll
    for (int i = 0; i < 4; ++i) acc[i] = (f32x4){0.f, 0.f, 0.f, 0.f};
    #pragma unroll
    for (int kk = 0; kk < 4; ++kk) {
        const float4* ap = (const float4*)(A + (size_t)am * 128 + kk * 32 + quad * 8);
        float4 a0 = ap[0], a1 = ap[1];
        short8 af;
        af[0] = f2bf(a0.x); af[1] = f2bf(a0.y); af[2] = f2bf(a0.z); af[3] = f2bf(a0.w);
        af[4] = f2bf(a1.x); af[5] = f2bf(a1.y); af[6] = f2bf(a1.z); af[7] = f2bf(a1.w);
        #pragma unroll
        for (int ns = 0; ns < 4; ++ns) {
            short8 wf = *(const short8*)&Wt[(ns * 16 + c16) * 136 + kk * 32 + quad * 8];
            acc[ns] = __builtin_amdgcn_mfma_f32_16x16x32_bf16(af, wf, acc[ns], 0, 0, 0);
        }
    }
    const int region = __builtin_amdgcn_readfirstlane(n0 >> 7);  // 0 Q, 1 K, 2 V
    #pragma unroll
    for (int ns = 0; ns < 4; ++ns) {
        const int n = n0 + ns * 16 + c16;
        float bv = bias[n];
        #pragma unroll
        for (int r = 0; r < 4; ++r) {
            const int row = m0 + wave * 16 + quad * 4 + r;
            float v = acc[ns][r] + bv;
            if (region == 0)      Qbf[(size_t)row * 128 + n] = f2bf(v * SC);
            else if (region == 1) Kbf[(size_t)row * 128 + (n - 128)] = f2bf(v);
            else                  VTb[(size_t)(n - 256) * SEQP2 + row] = f2bf(v);
        }
    }
}

// ---- FUSED mlp1+mlp2-kpart: grid (40 M-tiles, 8 kz). Block computes the 64x64
// gelu(H@W1+b1) tile for n0=64*kz, then (wave-internal LDS C->A round-trip, no
// block barrier) uses it as A for mlp2 K-slice [64kz,64kz+64) -> PARTG[kz].
// The mlp1 intermediate never touches HBM.
__global__ __launch_bounds__(256) void mlp_fused_kernel(
    const float* __restrict__ A, const float* __restrict__ W1,
    const float* __restrict__ b1, const float* __restrict__ W2,
    float* __restrict__ PARTG) {
    __shared__ __align__(16) short W1t[64 * 136];   // 17.4 KB
    __shared__ __align__(16) short W2t[128 * 72];   // 18.4 KB
    __shared__ __align__(16) short Ct[4 * 16 * 72]; //  9.2 KB (per-wave 16x72)
    const int t = threadIdx.x;
    const int wave = t >> 6, lane = t & 63;
    const int quad = lane >> 4, c16 = lane & 15;
    const int m0 = blockIdx.x * 64;
    const int kz = blockIdx.y;
    const int n0 = kz * 64;
    // stage W1[0:128][n0:n0+64]
    #pragma unroll
    for (int pass = 0; pass < 4; ++pass) {
        int idx = t + pass * 256;
        int n = idx & 63, kc = idx >> 6;
        short8 wv;
        #pragma unroll
        for (int j = 0; j < 8; ++j)
            wv[j] = f2bf(W1[(size_t)(kc * 8 + j) * 512 + n0 + n]);
        *(short8*)&W1t[n * 136 + kc * 8] = wv;
    }
    // stage W2[n0:n0+64][0:128]
    {
        const int n = t & 127, half = t >> 7;
        #pragma unroll
        for (int c = 0; c < 4; ++c) {
            short8 wv;
            #pragma unroll
            for (int j = 0; j < 8; ++j)
                wv[j] = f2bf(W2[(size_t)(n0 + half * 32 + c * 8 + j) * 128 + n]);
            *(short8*)&W2t[n * 72 + half * 32 + c * 8] = wv;
        }
    }
    __syncthreads();
    const int am = m0 + wave * 16 + c16;
    // mlp1: 64x64 tile
    f32x4 acc1[4];
    #pragma unroll
    for (int i = 0; i < 4; ++i) acc1[i] = (f32x4){0.f, 0.f, 0.f, 0.f};
    #pragma unroll
    for (int kk = 0; kk < 4; ++kk) {
        const float4* ap = (const float4*)(A + (size_t)am * 128 + kk * 32 + quad * 8);
        float4 a0 = ap[0], a1 = ap[1];
        short8 af;
        af[0] = f2bf(a0.x); af[1] = f2bf(a0.y); af[2] = f2bf(a0.z); af[3] = f2bf(a0.w);
        af[4] = f2bf(a1.x); af[5] = f2bf(a1.y); af[6] = f2bf(a1.z); af[7] = f2bf(a1.w);
        #pragma unroll
        for (int ns = 0; ns < 4; ++ns) {
            short8 wf = *(const short8*)&W1t[(ns * 16 + c16) * 136 + kk * 32 + quad * 8];
            acc1[ns] = __builtin_amdgcn_mfma_f32_16x16x32_bf16(af, wf, acc1[ns], 0, 0, 0);
        }
    }
    // gelu + bias -> bf16 -> per-wave Ct (C-layout write: row=quad*4+r, col=ns*16+c16)
    short* Cw = Ct + wave * 16 * 72;
    #pragma unroll
    for (int ns = 0; ns < 4; ++ns) {
        float bv = b1[n0 + ns * 16 + c16];
        #pragma unroll
        for (int r = 0; r < 4; ++r)
            Cw[(quad * 4 + r) * 72 + ns * 16 + c16] = f2bf(gelu_exact(acc1[ns][r] + bv));
    }
    // mlp2 partial: A-frag read (wave-internal: rows wave*16+c16 written above by this wave)
    f32x4 acc2[8];
    #pragma unroll
    for (int i = 0; i < 8; ++i) acc2[i] = (f32x4){0.f, 0.f, 0.f, 0.f};
    #pragma unroll
    for (int kk = 0; kk < 2; ++kk) {
        short8 af2 = *(const short8*)&Cw[c16 * 72 + kk * 32 + quad * 8];
        #pragma unroll
        for (int ns = 0; ns < 8; ++ns) {
            short8 wf = *(const short8*)&W2t[(ns * 16 + c16) * 72 + kk * 32 + quad * 8];
            acc2[ns] = __builtin_amdgcn_mfma_f32_16x16x32_bf16(af2, wf, acc2[ns], 0, 0, 0);
        }
    }
    float* dst = PARTG + (size_t)kz * SEQP2 * 128;
    #pragma unroll
    for (int ns = 0; ns < 8; ++ns) {
        #pragma unroll
        for (int r = 0; r < 4; ++r) {
            const int row = m0 + wave * 16 + quad * 4 + r;
            dst[(size_t)row * 128 + ns * 16 + c16] = acc2[ns][r];
        }
    }
}

// ---- combine 8 K-split partials + bias + residual + row-LN ---------------------
__global__ __launch_bounds__(512) void combine_ln_kernel(
    const float* __restrict__ PARTG, const float* __restrict__ bias,
    const float* __restrict__ R, float* __restrict__ C, float* __restrict__ H,
    const float* __restrict__ g, const float* __restrict__ bb, int M) {
    __shared__ float ln[8][130];
    const int t = threadIdx.x;
    const int c = t & 127;
    const int grp = __builtin_amdgcn_readfirstlane(t >> 7);
    const int r0 = blockIdx.x * 8 + grp * 2;
    #pragma unroll
    for (int i = 0; i < 2; ++i) {
        const int row = r0 + i;
        float v = bias[c] + R[(size_t)row * 128 + c];
        #pragma unroll
        for (int kz = 0; kz < 8; ++kz)
            v += PARTG[(size_t)kz * SEQP2 * 128 + (size_t)row * 128 + c];
        ln[grp * 2 + i][c] = v;
        if (row < M) C[(size_t)row * 128 + c] = v;
    }
    __syncthreads();
    const int wv = t >> 6, l = t & 63;
    float x0 = ln[wv][l], x1 = ln[wv][l + 64];
    float s = x0 + x1;
    for (int off = 32; off > 0; off >>= 1) s += __shfl_down(s, off);
    float mean = __shfl(s, 0) * (1.f / 128.f);
    float d0 = x0 - mean, d1 = x1 - mean;
    float vv = d0 * d0 + d1 * d1;
    for (int off = 32; off > 0; off >>= 1) vv += __shfl_down(vv, off);
    float var = __shfl(vv, 0) * (1.f / 128.f);
    float rstd = rsqrtf(var + 1e-5f);
    const int hrow = blockIdx.x * 8 + wv;
    H[(size_t)hrow * 128 + l]      = d0 * rstd * g[l] + bb[l];
    H[(size_t)hrow * 128 + 64 + l] = d1 * rstd * g[l + 64] + bb[l + 64];
}

// ---- proj GEMM fused with attn 2-way split merge + residual + row-LN -----------
__global__ __launch_bounds__(512) void proj_merge_ln_kernel(
    const float* __restrict__ PART, const float* __restrict__ W,
    const float* __restrict__ bias, const float* __restrict__ R,
    float* __restrict__ C, float* __restrict__ H,
    const float* __restrict__ g, const float* __restrict__ bb, int M) {
    __shared__ float ln[8][130];
    const int t = threadIdx.x;
    const int c = t & 127;
    const int grp = __builtin_amdgcn_readfirstlane(t >> 7);
    const int r0 = blockIdx.x * 8 + grp * 2;
    float acc0 = 0.f, acc1 = 0.f;
    #pragma unroll
    for (int h = 0; h < 8; ++h) {
        const float* p0a = PART + ((size_t)h * SEQP + r0) * 20;
        const float* p1a = PART + ((size_t)(8 + h) * SEQP + r0) * 20;
        const float* p0b = p0a + 20;
        const float* p1b = p1a + 20;
        float m0 = p0a[16], l0 = p0a[17], m1 = p1a[16], l1 = p1a[17];
        float Ma = fmaxf(m0, m1);
        float w0 = fexp2(m0 - Ma), w1 = fexp2(m1 - Ma);
        float inva = 1.f / fmaf(l0, w0, l1 * w1);
        float c0a = w0 * inva, c1a = w1 * inva;
        m0 = p0b[16]; l0 = p0b[17]; m1 = p1b[16]; l1 = p1b[17];
        float Mb = fmaxf(m0, m1);
        w0 = fexp2(m0 - Mb); w1 = fexp2(m1 - Mb);
        float invb = 1.f / fmaf(l0, w0, l1 * w1);
        float c0b = w0 * invb, c1b = w1 * invb;
        #pragma unroll
        for (int kk = 0; kk < 4; ++kk) {
            const int k0 = h * 16 + kk * 4;
            float w_0 = W[(size_t)(k0 + 0) * 128 + c];
            float w_1 = W[(size_t)(k0 + 1) * 128 + c];
            float w_2 = W[(size_t)(k0 + 2) * 128 + c];
            float w_3 = W[(size_t)(k0 + 3) * 128 + c];
            float4 x0 = *(const float4*)&p0a[kk * 4];
            float4 y0 = *(const float4*)&p1a[kk * 4];
            float4 x1 = *(const float4*)&p0b[kk * 4];
            float4 y1 = *(const float4*)&p1b[kk * 4];
            float a00 = x0.x * c0a + y0.x * c1a;
            float a01 = x0.y * c0a + y0.y * c1a;
            float a02 = x0.z * c0a + y0.z * c1a;
            float a03 = x0.w * c0a + y0.w * c1a;
            float a10 = x1.x * c0b + y1.x * c1b;
            float a11 = x1.y * c0b + y1.y * c1b;
            float a12 = x1.z * c0b + y1.z * c1b;
            float a13 = x1.w * c0b + y1.w * c1b;
            acc0 = fmaf(a00, w_0, acc0); acc0 = fmaf(a01, w_1, acc0);
            acc0 = fmaf(a02, w_2, acc0); acc0 = fmaf(a03, w_3, acc0);
            acc1 = fmaf(a10, w_0, acc1); acc1 = fmaf(a11, w_1, acc1);
            acc1 = fmaf(a12, w_2, acc1); acc1 = fmaf(a13, w_3, acc1);
        }
    }
    float bv = bias[c];
    float v0 = acc0 + bv + R[(size_t)(r0 + 0) * 128 + c];
    float v1 = acc1 + bv + R[(size_t)(r0 + 1) * 128 + c];
    ln[grp * 2 + 0][c] = v0;
    ln[grp * 2 + 1][c] = v1;
    if (r0 + 0 < M) C[(size_t)(r0 + 0) * 128 + c] = v0;
    if (r0 + 1 < M) C[(size_t)(r0 + 1) * 128 + c] = v1;
    __syncthreads();
    const int wv = t >> 6, l = t & 63;
    float x0 = ln[wv][l], x1 = ln[wv][l + 64];
    float s = x0 + x1;
    for (int off = 32; off > 0; off >>= 1) s += __shfl_down(s, off);
    float mean = __shfl(s, 0) * (1.f / 128.f);
    float d0 = x0 - mean, d1 = x1 - mean;
    float vv = d0 * d0 + d1 * d1;
    for (int off = 32; off > 0; off >>= 1) vv += __shfl_down(vv, off);
    float var = __shfl(vv, 0) * (1.f / 128.f);
    float rstd = rsqrtf(var + 1e-5f);
    const int hrow = blockIdx.x * 8 + wv;
    H[(size_t)hrow * 128 + l]      = d0 * rstd * g[l] + bb[l];
    H[(size_t)hrow * 128 + 64 + l] = d1 * rstd * g[l + 64] + bb[l + 64];
}

// ---- attention: bf16 MFMA flash, pre-converted inputs, split-K=2 ---------------
__global__ __launch_bounds__(128) void attn_kernel(
    const short* __restrict__ Qbf, const short* __restrict__ Kbf,
    const short* __restrict__ VTb, float* __restrict__ PART) {
    __shared__ __align__(16) short sKs[9600];  // Ks 128*24 | Vt 16*136 | P 2*16*136
    short* Ks = sKs;
    short* Vt = sKs + 3072;
    const int t = threadIdx.x;
    const int wave = t >> 6, lane = t & 63;
    const int quad = lane >> 4, c16 = lane & 15;
    short* Pw = sKs + 3072 + 2176 + wave * 16 * 136;
    const int head = blockIdx.y, z = blockIdx.z;
    const int qb = blockIdx.x * 32 + wave * 16;

    short8 qf;
    #pragma unroll
    for (int i = 0; i < 8; ++i) qf[i] = 0;
    if (quad < 2)
        qf = *(const short8*)(Qbf + (size_t)(qb + c16) * 128 + head * 16 + quad * 8);
    f32x4 oacc = {0.f, 0.f, 0.f, 0.f};
    float m_[4] = {-INFINITY, -INFINITY, -INFINITY, -INFINITY};
    float l_[4] = {0.f, 0.f, 0.f, 0.f};

    const int vdim = t >> 3, vseg = t & 7;
    const int tA = z * 10, tB = z ? 20 : 10;
    for (int ti = tA; ti < tB; ++ti) {
        const int tile0 = ti * 128;
        if (ti != tA) __syncthreads();
        {
            const short8* kp = (const short8*)(Kbf + (size_t)(tile0 + t) * 128 + head * 16);
            *(short8*)&Ks[t * 24]     = kp[0];
            *(short8*)&Ks[t * 24 + 8] = kp[1];
            const short8* vp = (const short8*)(VTb + (size_t)(head * 16 + vdim) * SEQP2 + tile0 + vseg * 16);
            *(short8*)&Vt[vdim * 136 + vseg * 16]     = vp[0];
            *(short8*)&Vt[vdim * 136 + vseg * 16 + 8] = vp[1];
        }
        __syncthreads();

        f32x4 sA[4], sB[4];
        #pragma unroll
        for (int st = 0; st < 4; ++st) {
            const int k0 = st * 32;
            short8 kfA, kfB;
            #pragma unroll
            for (int i = 0; i < 8; ++i) { kfA[i] = 0; kfB[i] = 0; }
            if (quad < 2) {
                kfA = *(const short8*)&Ks[(k0 + c16) * 24 + quad * 8];
                kfB = *(const short8*)&Ks[(k0 + 16 + c16) * 24 + quad * 8];
            }
            f32x4 zz = {0.f, 0.f, 0.f, 0.f};
            sA[st] = __builtin_amdgcn_mfma_f32_16x16x32_bf16(qf, kfA, zz, 0, 0, 0);
            sB[st] = __builtin_amdgcn_mfma_f32_16x16x32_bf16(qf, kfB, zz, 0, 0, 0);
            const bool badA = (tile0 + k0 + c16) >= SEQ;
            const bool badB = (tile0 + k0 + 16 + c16) >= SEQ;
            if (badA) { sA[st][0] = -1e30f; sA[st][1] = -1e30f; sA[st][2] = -1e30f; sA[st][3] = -1e30f; }
            if (badB) { sB[st][0] = -1e30f; sB[st][1] = -1e30f; sB[st][2] = -1e30f; sB[st][3] = -1e30f; }
        }
        #pragma unroll
        for (int r = 0; r < 4; ++r) {
            float v = fmaxf(sA[0][r], sB[0][r]);
            #pragma unroll
            for (int st = 1; st < 4; ++st) v = fmaxf(v, fmaxf(sA[st][r], sB[st][r]));
            v = fmaxf(v, __shfl_xor(v, 1));
            v = fmaxf(v, __shfl_xor(v, 2));
            v = fmaxf(v, __shfl_xor(v, 4));
            v = fmaxf(v, __shfl_xor(v, 8));
            float nm = fmaxf(m_[r], v);
            float corr = fexp2(m_[r] - nm);
            m_[r] = nm;
            oacc[r] *= corr;
            l_[r] *= corr;
        }
        #pragma unroll
        for (int st = 0; st < 4; ++st) {
            #pragma unroll
            for (int r = 0; r < 4; ++r) {
                float eA = fexp2(sA[st][r] - m_[r]);
                float eB = fexp2(sB[st][r] - m_[r]);
                l_[r] += eA + eB;
                Pw[(quad * 4 + r) * 136 + st * 32 + c16]      = f2bf_trunc(eA);
                Pw[(quad * 4 + r) * 136 + st * 32 + 16 + c16] = f2bf_trunc(eB);
            }
        }
        #pragma unroll
        for (int st = 0; st < 4; ++st) {
            short8 pf = *(const short8*)&Pw[c16 * 136 + st * 32 + quad * 8];
            short8 vf = *(const short8*)&Vt[c16 * 136 + st * 32 + quad * 8];
            oacc = __builtin_amdgcn_mfma_f32_16x16x32_bf16(pf, vf, oacc, 0, 0, 0);
        }
    }
    #pragma unroll
    for (int r = 0; r < 4; ++r) {
        float lr = l_[r];
        lr += __shfl_xor(lr, 1);
        lr += __shfl_xor(lr, 2);
        lr += __shfl_xor(lr, 4);
        lr += __shfl_xor(lr, 8);
        const int qrow = qb + quad * 4 + r;
        if (qrow < SEQ) {
            float* dst = PART + ((size_t)(z * 8 + head) * SEQP + qrow) * 20;
            dst[c16] = oacc[r];
            if (c16 == 0) { dst[16] = m_[r]; dst[17] = lr; }
        }
    }
}

// ---- region + map_fuse + channel-LN stats (fused) ------------------------------
__global__ __launch_bounds__(256) void region_fuse_stats_kernel(
    const float* __restrict__ sup, const float* __restrict__ qry,
    const float* __restrict__ X, float* __restrict__ fused,
    float* __restrict__ MEAN, float* __restrict__ RSTD) {
    __shared__ float key0[2048];
    __shared__ float rfac[100];
    const int b = blockIdx.x;
    const int t = threadIdx.x;
    const float* feat = (b < 25) ? (sup + (size_t)b * 12800) : (qry + (size_t)(b - 25) * 12800);
    for (int i = t; i < 2048; i += 256) key0[i] = X[i];
    __syncthreads();
    if (t < 100) {
        float dots[16];
        #pragma unroll
        for (int mm = 0; mm < 16; ++mm) dots[mm] = 0.f;
        float s = 0.f, ss = 0.f;
        for (int c = 0; c < 128; ++c) {
            float f = feat[c * 100 + t];
            s += f; ss += f * f;
            #pragma unroll
            for (int mm = 0; mm < 16; ++mm) dots[mm] += f * key0[mm * 128 + c];
        }
        float mean16 = 0.f;
        #pragma unroll
        for (int mm = 0; mm < 16; ++mm) mean16 += 1.f / (1.f + expf(-dots[mm] * (1.f / 128.f)));
        float r = mean16 * (1.f / 16.f) + 1.f;
        rfac[t] = r;
        float mr = s * (1.f / 128.f);
        float vr = ss * (1.f / 128.f) - mr * mr;
        MEAN[b * 128 + t] = mr * r;
        RSTD[b * 128 + t] = rsqrtf(vr * r * r + 1e-6f);
    }
    __syncthreads();
    for (int i = t; i < 12800; i += 256)
        fused[(size_t)b * 12800 + i] = feat[i] * rfac[i % 100];
}

// ---- conv1 split over input channels: grid (100, 4 to-groups, 4 cin-chunks) ----
__global__ __launch_bounds__(256) void conv1_split_kernel(
    const float* __restrict__ in, const float* __restrict__ w,
    const float* __restrict__ MEAN, const float* __restrict__ RSTD,
    const float* __restrict__ g, const float* __restrict__ bb,
    float* __restrict__ PARTC) {
    __shared__ float sin_[32 * 144];
    const int b = blockIdx.x;
    const int base_to = blockIdx.y * 8;
    const int cb = blockIdx.z * 32;
    const int t = threadIdx.x;
    const int h = __builtin_amdgcn_readfirstlane(t >> 7);
    const int p = t & 127;
    const int py = p / 10, px = p - py * 10;
    const bool active = p < 100;
    float acc[4] = {0.f, 0.f, 0.f, 0.f};
    for (int i = t; i < 32 * 144; i += 256) {
        int c = i / 144, pos = i - c * 144;
        int y = pos / 12 - 1, x = pos % 12 - 1;
        float v = 0.f;
        if ((unsigned)y < 10u && (unsigned)x < 10u) {
            int pp = y * 10 + x;
            float raw = in[(size_t)b * 12800 + (cb + c) * 100 + pp];
            v = (raw - MEAN[b * 128 + pp]) * RSTD[b * 128 + pp] * g[cb + c] + bb[cb + c];
        }
        sin_[i] = v;
    }
    __syncthreads();
    if (active) {
        const float* wbase = w + ((size_t)(base_to + h * 4) * 128 + cb) * 9;
        for (int c = 0; c < 32; ++c) {
            const float* sp = &sin_[c * 144 + py * 12 + px];
            float pix[9];
            #pragma unroll
            for (int k = 0; k < 9; ++k) pix[k] = sp[(k / 3) * 12 + (k % 3)];
            #pragma unroll
            for (int j = 0; j < 4; ++j) {
                const float* wq = wbase + ((size_t)j * 128 + c) * 9;
                #pragma unroll
                for (int k = 0; k < 9; ++k) acc[j] = fmaf(pix[k], wq[k], acc[j]);
            }
        }
        #pragma unroll
        for (int j = 0; j < 4; ++j)
            PARTC[((size_t)blockIdx.z * 100 + b) * 3200 + (base_to + h * 4 + j) * 100 + p] = acc[j];
    }
}

// ------- 3x3 conv (CIN=32), pad 1, grid (100, 8): 2 to-ch per half-block --------
template<bool RELU, bool COMBINE>
__global__ __launch_bounds__(256) void conv3x3_to4_kernel(
    const float* __restrict__ in, const float* __restrict__ w,
    float* __restrict__ out) {
    __shared__ float sin_[32 * 144];
    const int b = blockIdx.x;
    const int base_to = blockIdx.y * 4;
    const int t = threadIdx.x;
    const int h = __builtin_amdgcn_readfirstlane(t >> 7);
    const int p = t & 127;
    const int py = p / 10, px = p - py * 10;
    const bool active = p < 100;
    float acc[2] = {0.f, 0.f};
    for (int i = t; i < 32 * 144; i += 256) {
        int c = i / 144, pos = i - c * 144;
        int y = pos / 12 - 1, x = pos % 12 - 1;
        float v = 0.f;
        if ((unsigned)y < 10u && (unsigned)x < 10u) {
            if (COMBINE) {
                const size_t base = (size_t)b * 3200 + c * 100 + y * 10 + x;
                v = in[base] + in[base + 320000] + in[base + 640000] + in[base + 960000];
                v = fmaxf(v, 0.f);
            } else {
                v = in[(size_t)b * 3200 + c * 100 + y * 10 + x];
            }
        }
        sin_[i] = v;
    }
    __syncthreads();
    if (active) {
        const float* wbase = w + ((size_t)(base_to + h * 2) * 32) * 9;
        for (int c = 0; c < 32; ++c) {
            const float* sp = &sin_[c * 144 + py * 12 + px];
            float pix[9];
            #pragma unroll
            for (int k = 0; k < 9; ++k) pix[k] = sp[(k / 3) * 12 + (k % 3)];
            #pragma unroll
            for (int j = 0; j < 2; ++j) {
                const float* wq = wbase + ((size_t)j * 32 + c) * 9;
                #pragma unroll
                for (int k = 0; k < 9; ++k) acc[j] = fmaf(pix[k], wq[k], acc[j]);
            }
        }
        #pragma unroll
        for (int j = 0; j < 2; ++j) {
            float v = acc[j];
            if (RELU) v = fmaxf(v, 0.f);
            out[(size_t)b * 3200 + (base_to + h * 2 + j) * 100 + p] = v;
        }
    }
}

// ---- conv4 fused with sigmoid-weighted pooling (rfm output) --------------------
__global__ __launch_bounds__(256) void conv4_rfm_kernel(
    const float* __restrict__ in, const float* __restrict__ w,
    const float* __restrict__ fused, float* __restrict__ out) {
    __shared__ float sin_[32 * 144];
    __shared__ float sig[4][104];
    const int b = blockIdx.x;
    const int base_to = blockIdx.y * 4;
    const int t = threadIdx.x;
    const int h = __builtin_amdgcn_readfirstlane(t >> 7);
    const int p = t & 127;
    const int py = p / 10, px = p - py * 10;
    const bool active = p < 100;
    float acc[2] = {0.f, 0.f};
    for (int i = t; i < 32 * 144; i += 256) {
        int c = i / 144, pos = i - c * 144;
        int y = pos / 12 - 1, x = pos % 12 - 1;
        float v = 0.f;
        if ((unsigned)y < 10u && (unsigned)x < 10u)
            v = in[(size_t)b * 3200 + c * 100 + y * 10 + x];
        sin_[i] = v;
    }
    __syncthreads();
    if (active) {
        const float* wbase = w + ((size_t)(base_to + h * 2) * 32) * 9;
        for (int c = 0; c < 32; ++c) {
            const float* sp = &sin_[c * 144 + py * 12 + px];
            float pix[9];
            #pragma unroll
            for (int k = 0; k < 9; ++k) pix[k] = sp[(k / 3) * 12 + (k % 3)];
            #pragma unroll
            for (int j = 0; j < 2; ++j) {
                const float* wq = wbase + ((size_t)j * 32 + c) * 9;
                #pragma unroll
                for (int k = 0; k < 9; ++k) acc[j] = fmaf(pix[k], wq[k], acc[j]);
            }
        }
        sig[h * 2 + 0][p] = 1.f / (1.f + expf(-acc[0]));
        sig[h * 2 + 1][p] = 1.f / (1.f + expf(-acc[1]));
    }
    __syncthreads();
    #pragma unroll
    for (int rep = 0; rep < 2; ++rep) {
        const int o = t + rep * 256;
        const int cc = o >> 2, ttl = o & 3;
        const float* fp = fused + (size_t)b * 12800 + cc * 100;
        float s = 0.f;
        for (int pp = 0; pp < 100; pp += 4) {
            float4 f4 = *(const float4*)&fp[pp];
            s += sig[ttl][pp] * f4.x + sig[ttl][pp + 1] * f4.y
               + sig[ttl][pp + 2] * f4.z + sig[ttl][pp + 3] * f4.w;
        }
        out[(size_t)b * 4096 + cc * 32 + base_to + ttl] = s * 0.01f;
    }
}

extern "C" void kernel_launch(void* const* d_in, const int* in_sizes, int n_in,
                              void* d_out, int out_size, void* d_ws, size_t ws_size,
                              hipStream_t stream) {
    (void)in_sizes; (void)n_in; (void)out_size; (void)ws_size;
    const float* sup    = (const float*)d_in[0];
    const float* qry    = (const float*)d_in[1];
    const float* td     = (const float*)d_in[2];
    const float* ln1_g  = (const float*)d_in[3];
    const float* ln1_b  = (const float*)d_in[4];
    const float* qkv_w  = (const float*)d_in[5];
    const float* qkv_b  = (const float*)d_in[6];
    const float* out_w  = (const float*)d_in[7];
    const float* out_b  = (const float*)d_in[8];
    const float* ln2_g  = (const float*)d_in[9];
    const float* ln2_b  = (const float*)d_in[10];
    const float* mlp_w1 = (const float*)d_in[11];
    const float* mlp_b1 = (const float*)d_in[12];
    const float* mlp_w2 = (const float*)d_in[13];
    const float* mlp_b2 = (const float*)d_in[14];
    const float* rg     = (const float*)d_in[15];
    const float* rb     = (const float*)d_in[16];
    const float* c1     = (const float*)d_in[17];
    const float* c2     = (const float*)d_in[18];
    const float* c3     = (const float*)d_in[19];
    const float* c4     = (const float*)d_in[20];
    float* out = (float*)d_out;

    float* ws   = (float*)d_ws;
    float* X    = ws;                  // 327680
    float* H    = X + 327680;          // 327680
    float* PARTC= H + 327680;          // 1280000 (conv1 partials)
    float* FUSED= PARTC + 1280000;     // 1280000
    float* MEAN = FUSED + 1280000;     // 12800
    float* RSTD = MEAN + 12800;        // 12800
    float* CB1  = RSTD + 12800;        // 320000
    float* CB2  = CB1 + 320000;        // 320000
    short* Qbf  = (short*)(CB2 + 320000);    // 2560*128 shorts
    short* Kbf  = Qbf + 327680;              // 2560*128 shorts
    short* VTb  = Kbf + 327680;              // 128*2560 shorts
    float* PARTG= (float*)(VTb + 327680);    // 8*2560*128 floats
    // PART (attn split partials, 2*8*2520*20 = 806400 floats) aliases PARTG:
    // PART dies inside proj_merge, PARTG born at mlp_fused.
    float* PART = PARTG;

    const int SG = (SEQ + 7) / 8;      // 315 blocks
    const int MT = (SEQ + 63) / 64;    // 40 M-tiles

    concat_ln_kernel<<<SEQ, 64, 0, stream>>>(td, sup, ln1_g, ln1_b, X, H);
    for (int i = 0; i < 2; ++i) {
        qkv_mfma_kernel<<<dim3(MT, 6), 256, 0, stream>>>(
            H, qkv_w + (size_t)i * 128 * 384, qkv_b + i * 384, Qbf, Kbf, VTb);
        attn_kernel<<<dim3((SEQ + 31) / 32, 8, 2), 128, 0, stream>>>(Qbf, Kbf, VTb, PART);
        proj_merge_ln_kernel<<<SG, 512, 0, stream>>>(
            PART, out_w + (size_t)i * 128 * 128, out_b + i * 128, X, X, H,
            ln2_g + i * 128, ln2_b + i * 128, SEQ);
        mlp_fused_kernel<<<dim3(MT, 8), 256, 0, stream>>>(
            H, mlp_w1 + (size_t)i * 128 * 512, mlp_b1 + i * 512,
            mlp_w2 + (size_t)i * 512 * 128, PARTG);
        const float* ng = (i == 0) ? ln1_g + 128 : ln1_g;
        const float* nb = (i == 0) ? ln1_b + 128 : ln1_b;
        combine_ln_kernel<<<SG, 512, 0, stream>>>(
            PARTG, mlp_b2 + i * 128, X, X, H, ng, nb, SEQ);
    }
    region_fuse_stats_kernel<<<100, 256, 0, stream>>>(sup, qry, X, FUSED, MEAN, RSTD);
    conv1_split_kernel<<<dim3(100, 4, 4), 256, 0, stream>>>(FUSED, c1, MEAN, RSTD, rg, rb, PARTC);
    conv3x3_to4_kernel<true,  true ><<<dim3(100, 8), 256, 0, stream>>>(PARTC, c2, CB2);
    conv3x3_to4_kernel<true,  false><<<dim3(100, 8), 256, 0, stream>>>(CB2, c3, CB1);
    conv4_rfm_kernel<<<dim3(100, 8), 256, 0, stream>>>(CB1, c4, FUSED, out);
}